// Round 1
// baseline (629.318 us; speedup 1.0000x reference)
//
#include <hip/hip_runtime.h>

#define BSZ 4
#define NPATCH 256
#define DIM 384
#define HID 2688
#define NCLS 1000
#define KTOT 2048
#define IMGSZ 224
#define PCH 14
#define GRD 16

static constexpr float INV_BETA = 1.0f / 0.07f;
static constexpr float LN_EPS_F = 1e-6f;

#define LDSP 72  // padded LDS row stride (floats) to break bank conflicts

// ---------------------------------------------------------------------------
// per-patch class histogram: labels (4,1,224,224) int32 -> label (4,256,1000)
// ---------------------------------------------------------------------------
__global__ __launch_bounds__(256) void patch_hist_kernel(
    const int* __restrict__ labels, float* __restrict__ label_out)
{
    int bp = blockIdx.x;            // b*256 + p
    int b = bp >> 8, p = bp & 255;
    int py = p >> 4, px = p & 15;
    __shared__ int hist[NCLS];
    int t = threadIdx.x;
    for (int c = t; c < NCLS; c += 256) hist[c] = 0;
    __syncthreads();
    if (t < PCH * PCH) {
        int dy = t / PCH, dx = t % PCH;
        int y = py * PCH + dy, x = px * PCH + dx;
        int lab = labels[(size_t)b * IMGSZ * IMGSZ + y * IMGSZ + x];
        atomicAdd(&hist[lab], 1);
    }
    __syncthreads();
    const float inv = 1.0f / (PCH * PCH);
    for (int c = t; c < NCLS; c += 256)
        label_out[(size_t)bp * NCLS + c] = hist[c] * inv;
}

// ---------------------------------------------------------------------------
// fc1 + erf-GELU: X (2048,384) @ W (384,2688) + b -> H (2048,2688)
// rows 0..1023 from Xt, 1024..2047 from Xr
// ---------------------------------------------------------------------------
__global__ __launch_bounds__(256) void fc1_gelu_kernel(
    const float* __restrict__ Xt, const float* __restrict__ Xr,
    const float* __restrict__ W, const float* __restrict__ bias,
    float* __restrict__ H)
{
    __shared__ float As[16][LDSP];
    __shared__ float Bs[16][LDSP];
    const int tid = threadIdx.x;
    const int tn = tid & 15, tm = tid >> 4;
    const int m0 = blockIdx.y * 64, n0 = blockIdx.x * 64;
    float acc[4][4] = {};
    for (int k0 = 0; k0 < DIM; k0 += 16) {
        {
            const int c = tid & 15, r0 = tid >> 4;
            #pragma unroll
            for (int i = 0; i < 4; ++i) {
                int r = r0 + 16 * i;
                int gm = m0 + r;
                const float* X = (gm < 1024) ? Xt : Xr;
                As[c][r] = X[(size_t)(gm & 1023) * DIM + k0 + c];
            }
        }
        {
            const int j = tid & 63, c0 = tid >> 6;
            #pragma unroll
            for (int i = 0; i < 4; ++i) {
                int c = c0 + 4 * i;
                Bs[c][j] = W[(size_t)(k0 + c) * HID + n0 + j];
            }
        }
        __syncthreads();
        #pragma unroll
        for (int kk = 0; kk < 16; ++kk) {
            float4 av = *(const float4*)&As[kk][tm * 4];
            float4 bv = *(const float4*)&Bs[kk][tn * 4];
            float a[4] = {av.x, av.y, av.z, av.w};
            float bb[4] = {bv.x, bv.y, bv.z, bv.w};
            #pragma unroll
            for (int i = 0; i < 4; ++i)
                #pragma unroll
                for (int j = 0; j < 4; ++j)
                    acc[i][j] = fmaf(a[i], bb[j], acc[i][j]);
        }
        __syncthreads();
    }
    #pragma unroll
    for (int i = 0; i < 4; ++i) {
        int m = m0 + tm * 4 + i;
        #pragma unroll
        for (int j = 0; j < 4; ++j) {
            int n = n0 + tn * 4 + j;
            float v = acc[i][j] + bias[n];
            v = 0.5f * v * (1.0f + erff(v * 0.7071067811865476f));
            H[(size_t)m * HID + n] = v;
        }
    }
}

// ---------------------------------------------------------------------------
// fc2: H (2048,2688) @ W (2688,384) + b -> Yp (2048,384)
// ---------------------------------------------------------------------------
__global__ __launch_bounds__(256) void fc2_kernel(
    const float* __restrict__ H, const float* __restrict__ W,
    const float* __restrict__ bias, float* __restrict__ Yp)
{
    __shared__ float As[16][LDSP];
    __shared__ float Bs[16][LDSP];
    const int tid = threadIdx.x;
    const int tn = tid & 15, tm = tid >> 4;
    const int m0 = blockIdx.y * 64, n0 = blockIdx.x * 64;
    float acc[4][4] = {};
    for (int k0 = 0; k0 < HID; k0 += 16) {
        {
            const int c = tid & 15, r0 = tid >> 4;
            #pragma unroll
            for (int i = 0; i < 4; ++i) {
                int r = r0 + 16 * i;
                As[c][r] = H[(size_t)(m0 + r) * HID + k0 + c];
            }
        }
        {
            const int j = tid & 63, c0 = tid >> 6;
            #pragma unroll
            for (int i = 0; i < 4; ++i) {
                int c = c0 + 4 * i;
                Bs[c][j] = W[(size_t)(k0 + c) * DIM + n0 + j];
            }
        }
        __syncthreads();
        #pragma unroll
        for (int kk = 0; kk < 16; ++kk) {
            float4 av = *(const float4*)&As[kk][tm * 4];
            float4 bv = *(const float4*)&Bs[kk][tn * 4];
            float a[4] = {av.x, av.y, av.z, av.w};
            float bb[4] = {bv.x, bv.y, bv.z, bv.w};
            #pragma unroll
            for (int i = 0; i < 4; ++i)
                #pragma unroll
                for (int j = 0; j < 4; ++j)
                    acc[i][j] = fmaf(a[i], bb[j], acc[i][j]);
        }
        __syncthreads();
    }
    #pragma unroll
    for (int i = 0; i < 4; ++i) {
        int m = m0 + tm * 4 + i;
        #pragma unroll
        for (int j = 0; j < 4; ++j) {
            int n = n0 + tn * 4 + j;
            Yp[(size_t)m * DIM + n] = acc[i][j] + bias[n];
        }
    }
}

// ---------------------------------------------------------------------------
// LayerNorm + L2-normalize per row: Yp (2048,384) -> Z (2048,384)
// one wave per row
// ---------------------------------------------------------------------------
__device__ __forceinline__ float wave_sum(float v) {
    #pragma unroll
    for (int off = 32; off > 0; off >>= 1) v += __shfl_xor(v, off);
    return v;
}

__global__ __launch_bounds__(256) void ln_l2_kernel(
    const float* __restrict__ Yp, const float* __restrict__ w,
    const float* __restrict__ b, float* __restrict__ Z)
{
    int wid = threadIdx.x >> 6, lane = threadIdx.x & 63;
    int row = blockIdx.x * 4 + wid;
    const float* y = Yp + (size_t)row * DIM;
    float x[6];
    float s = 0.0f;
    #pragma unroll
    for (int i = 0; i < 6; ++i) { x[i] = y[lane + 64 * i]; s += x[i]; }
    s = wave_sum(s);
    float mu = s * (1.0f / DIM);
    float vs = 0.0f;
    #pragma unroll
    for (int i = 0; i < 6; ++i) { float d = x[i] - mu; vs += d * d; }
    vs = wave_sum(vs);
    float rstd = 1.0f / sqrtf(vs * (1.0f / DIM) + LN_EPS_F);
    float z[6];
    float n2 = 0.0f;
    #pragma unroll
    for (int i = 0; i < 6; ++i) {
        z[i] = (x[i] - mu) * rstd * w[lane + 64 * i] + b[lane + 64 * i];
        n2 += z[i] * z[i];
    }
    n2 = wave_sum(n2);
    float inv = 1.0f / fmaxf(sqrtf(n2), 1e-12f);
    #pragma unroll
    for (int i = 0; i < 6; ++i)
        Z[(size_t)row * DIM + lane + 64 * i] = z[i] * inv;
}

// ---------------------------------------------------------------------------
// QK^T (NT gemm with gathered B rows): per b, Zt (256,384) @ Zd^T -> S (256,2048)
// ---------------------------------------------------------------------------
__global__ __launch_bounds__(256) void qk_gemm_kernel(
    const float* __restrict__ Z, const int* __restrict__ perms,
    float* __restrict__ S)
{
    const int b = blockIdx.z;
    __shared__ int ap[8];
    if (threadIdx.x < 8)
        ap[threadIdx.x] = (threadIdx.x == 0) ? b : perms[(threadIdx.x - 1) * BSZ + b];
    __syncthreads();

    __shared__ float As[16][LDSP];
    __shared__ float Bs[16][LDSP];
    const int tid = threadIdx.x;
    const int tn = tid & 15, tm = tid >> 4;
    const int m0 = blockIdx.y * 64, n0 = blockIdx.x * 64;
    const float* Aq = Z + (size_t)b * NPATCH * DIM;       // queries (target rows)
    const float* Kb = Z + (size_t)1024 * DIM;             // ref rows base
    float acc[4][4] = {};
    for (int k0 = 0; k0 < DIM; k0 += 16) {
        {
            const int c = tid & 15, r0 = tid >> 4;
            #pragma unroll
            for (int i = 0; i < 4; ++i) {
                int r = r0 + 16 * i;
                As[c][r] = Aq[(size_t)(m0 + r) * DIM + k0 + c];
            }
        }
        {
            const int c = tid & 15, j0 = tid >> 4;
            #pragma unroll
            for (int i = 0; i < 4; ++i) {
                int j = j0 + 16 * i;
                int kg = n0 + j;
                int src = ap[kg >> 8] * NPATCH + (kg & 255);
                Bs[c][j] = Kb[(size_t)src * DIM + k0 + c];
            }
        }
        __syncthreads();
        #pragma unroll
        for (int kk = 0; kk < 16; ++kk) {
            float4 av = *(const float4*)&As[kk][tm * 4];
            float4 bv = *(const float4*)&Bs[kk][tn * 4];
            float a[4] = {av.x, av.y, av.z, av.w};
            float bb[4] = {bv.x, bv.y, bv.z, bv.w};
            #pragma unroll
            for (int i = 0; i < 4; ++i)
                #pragma unroll
                for (int j = 0; j < 4; ++j)
                    acc[i][j] = fmaf(a[i], bb[j], acc[i][j]);
        }
        __syncthreads();
    }
    #pragma unroll
    for (int i = 0; i < 4; ++i) {
        int m = m0 + tm * 4 + i;
        #pragma unroll
        for (int j = 0; j < 4; ++j) {
            int n = n0 + tn * 4 + j;
            S[((size_t)b * NPATCH + m) * KTOT + n] = acc[i][j];
        }
    }
}

// ---------------------------------------------------------------------------
// row softmax over 2048 with 1/beta scale, in place
// ---------------------------------------------------------------------------
__global__ __launch_bounds__(256) void softmax_kernel(float* __restrict__ S)
{
    int row = blockIdx.x;
    float* p = S + (size_t)row * KTOT;
    int t = threadIdx.x;
    float v[8];
    float m = -1e30f;
    #pragma unroll
    for (int i = 0; i < 8; ++i) {
        v[i] = p[t + 256 * i] * INV_BETA;
        m = fmaxf(m, v[i]);
    }
    #pragma unroll
    for (int off = 32; off > 0; off >>= 1) m = fmaxf(m, __shfl_xor(m, off));
    __shared__ float redm[4];
    __shared__ float reds[4];
    int wid = t >> 6;
    if ((t & 63) == 0) redm[wid] = m;
    __syncthreads();
    m = fmaxf(fmaxf(redm[0], redm[1]), fmaxf(redm[2], redm[3]));
    float s = 0.0f;
    #pragma unroll
    for (int i = 0; i < 8; ++i) { v[i] = expf(v[i] - m); s += v[i]; }
    s = wave_sum(s);
    if ((t & 63) == 0) reds[wid] = s;
    __syncthreads();
    s = reds[0] + reds[1] + reds[2] + reds[3];
    float inv = 1.0f / s;
    #pragma unroll
    for (int i = 0; i < 8; ++i) p[t + 256 * i] = v[i] * inv;
}

// ---------------------------------------------------------------------------
// PV (NN gemm with gathered B rows): attn (256,2048) @ Ld (2048,1000) -> lhat
// ---------------------------------------------------------------------------
__global__ __launch_bounds__(256) void pv_gemm_kernel(
    const float* __restrict__ Attn, const float* __restrict__ Lab,
    const int* __restrict__ perms, float* __restrict__ Lhat)
{
    const int b = blockIdx.z;
    __shared__ int ap[8];
    if (threadIdx.x < 8)
        ap[threadIdx.x] = (threadIdx.x == 0) ? b : perms[(threadIdx.x - 1) * BSZ + b];
    __syncthreads();

    __shared__ float As[16][LDSP];
    __shared__ float Bs[16][LDSP];
    const int tid = threadIdx.x;
    const int tn = tid & 15, tm = tid >> 4;
    const int m0 = blockIdx.y * 64, n0 = blockIdx.x * 64;
    const float* A = Attn + (size_t)b * NPATCH * KTOT;
    float acc[4][4] = {};
    for (int k0 = 0; k0 < KTOT; k0 += 16) {
        {
            const int c = tid & 15, r0 = tid >> 4;
            #pragma unroll
            for (int i = 0; i < 4; ++i) {
                int r = r0 + 16 * i;
                As[c][r] = A[(size_t)(m0 + r) * KTOT + k0 + c];
            }
        }
        {
            const int j = tid & 63, c0 = tid >> 6;
            #pragma unroll
            for (int i = 0; i < 4; ++i) {
                int c = c0 + 4 * i;
                int kg = k0 + c;
                int src = ap[kg >> 8] * NPATCH + (kg & 255);
                int n = n0 + j;
                Bs[c][j] = (n < NCLS) ? Lab[(size_t)src * NCLS + n] : 0.0f;
            }
        }
        __syncthreads();
        #pragma unroll
        for (int kk = 0; kk < 16; ++kk) {
            float4 av = *(const float4*)&As[kk][tm * 4];
            float4 bv = *(const float4*)&Bs[kk][tn * 4];
            float a[4] = {av.x, av.y, av.z, av.w};
            float bb[4] = {bv.x, bv.y, bv.z, bv.w};
            #pragma unroll
            for (int i = 0; i < 4; ++i)
                #pragma unroll
                for (int j = 0; j < 4; ++j)
                    acc[i][j] = fmaf(a[i], bb[j], acc[i][j]);
        }
        __syncthreads();
    }
    #pragma unroll
    for (int i = 0; i < 4; ++i) {
        int m = m0 + tm * 4 + i;
        #pragma unroll
        for (int j = 0; j < 4; ++j) {
            int n = n0 + tn * 4 + j;
            if (n < NCLS)
                Lhat[((size_t)b * NPATCH + m) * NCLS + n] = acc[i][j];
        }
    }
}

// ---------------------------------------------------------------------------
// nearest-upsample 16x16 -> 224x224 with (q,c)->(c,y,x) transpose
// one block per (b, c, gy): writes 14 rows of 224 floats
// ---------------------------------------------------------------------------
__global__ __launch_bounds__(256) void upsample_kernel(
    const float* __restrict__ Lhat, float* __restrict__ out)
{
    int blk = blockIdx.x;           // (b*NCLS + c)*GRD + gy
    int gy = blk & 15;
    int bc = blk >> 4;
    int c = bc % NCLS;
    int b = bc / NCLS;
    __shared__ float vals[GRD];
    int t = threadIdx.x;
    if (t < GRD)
        vals[t] = Lhat[((size_t)(b * NPATCH + gy * GRD + t)) * NCLS + c];
    __syncthreads();
    float* obase = out + ((size_t)(b * NCLS + c) * IMGSZ + gy * PCH) * IMGSZ;
    for (int idx = t; idx < PCH * 56; idx += 256) {
        int x4 = idx % 56, dy = idx / 56;
        int x0 = x4 * 4;
        float4 v = make_float4(vals[x0 / PCH], vals[(x0 + 1) / PCH],
                               vals[(x0 + 2) / PCH], vals[(x0 + 3) / PCH]);
        *(float4*)(obase + dy * IMGSZ + x0) = v;
    }
}

// ---------------------------------------------------------------------------
extern "C" void kernel_launch(void* const* d_in, const int* in_sizes, int n_in,
                              void* d_out, int out_size, void* d_ws, size_t ws_size,
                              hipStream_t stream)
{
    (void)in_sizes; (void)n_in; (void)out_size; (void)ws_size;
    const float* feat_t = (const float*)d_in[0];
    const float* feat_r = (const float*)d_in[1];
    const int*   labels = (const int*)d_in[2];
    const int*   perms  = (const int*)d_in[3];
    const float* fc1_w  = (const float*)d_in[4];
    const float* fc1_b  = (const float*)d_in[5];
    const float* fc2_w  = (const float*)d_in[6];
    const float* fc2_b  = (const float*)d_in[7];
    const float* ln_w   = (const float*)d_in[8];
    const float* ln_b   = (const float*)d_in[9];
    float* out = (float*)d_out;
    float* ws  = (float*)d_ws;

    // workspace layout (floats); Attn/Lhat alias H (H dead after fc2)
    float* H    = ws;                       // 2048*2688 = 5,505,024
    float* Attn = ws;                       // 4*256*2048 = 2,097,152 (aliases H)
    float* Lhat = ws + 2097152;             // 4*256*1000 = 1,024,000 (aliases H)
    float* Yp   = ws + 5505024;             // 2048*384 = 786,432
    float* Z    = Yp + 786432;              // 2048*384 = 786,432
    float* Lab  = Z + 786432;               // 4*256*1000 = 1,024,000

    patch_hist_kernel<<<dim3(BSZ * NPATCH), dim3(256), 0, stream>>>(labels, Lab);

    fc1_gelu_kernel<<<dim3(HID / 64, 2048 / 64), dim3(256), 0, stream>>>(
        feat_t, feat_r, fc1_w, fc1_b, H);

    fc2_kernel<<<dim3(DIM / 64, 2048 / 64), dim3(256), 0, stream>>>(
        H, fc2_w, fc2_b, Yp);

    ln_l2_kernel<<<dim3(2048 / 4), dim3(256), 0, stream>>>(Yp, ln_w, ln_b, Z);

    qk_gemm_kernel<<<dim3(KTOT / 64, NPATCH / 64, BSZ), dim3(256), 0, stream>>>(
        Z, perms, Attn);

    softmax_kernel<<<dim3(BSZ * NPATCH), dim3(256), 0, stream>>>(Attn);

    pv_gemm_kernel<<<dim3((NCLS + 63) / 64, NPATCH / 64, BSZ), dim3(256), 0, stream>>>(
        Attn, Lab, perms, Lhat);

    upsample_kernel<<<dim3(BSZ * NCLS * GRD), dim3(256), 0, stream>>>(Lhat, out);
}

// Round 2
// 407.197 us; speedup vs baseline: 1.5455x; 1.5455x over previous
//
#include <hip/hip_runtime.h>

#define BSZ 4
#define NPATCH 256
#define DIM 384
#define HID 2688
#define NCLS 1000
#define KTOT 2048
#define IMGSZ 224
#define PCH 14
#define GRD 16

static constexpr float INV_BETA = 1.0f / 0.07f;
static constexpr float LN_EPS_F = 1e-6f;

typedef unsigned short u16;
typedef unsigned int   u32;
typedef __attribute__((ext_vector_type(8))) __bf16 bf16x8;
typedef __attribute__((ext_vector_type(4))) float  f32x4;

__device__ __forceinline__ u16 f2bf(float f) {
    u32 u = __float_as_uint(f);
    return (u16)((u + 0x7FFFu + ((u >> 16) & 1u)) >> 16);
}
__device__ __forceinline__ float bf2f(u16 h) {
    return __uint_as_float(((u32)h) << 16);
}
__device__ __forceinline__ void split8(const float x[8], uint4& hi, uint4& lo) {
    u16 h[8], l[8];
    #pragma unroll
    for (int i = 0; i < 8; ++i) {
        h[i] = f2bf(x[i]);
        l[i] = f2bf(x[i] - bf2f(h[i]));
    }
    hi = make_uint4((u32)h[0] | ((u32)h[1] << 16), (u32)h[2] | ((u32)h[3] << 16),
                    (u32)h[4] | ((u32)h[5] << 16), (u32)h[6] | ((u32)h[7] << 16));
    lo = make_uint4((u32)l[0] | ((u32)l[1] << 16), (u32)l[2] | ((u32)l[3] << 16),
                    (u32)l[4] | ((u32)l[5] << 16), (u32)l[6] | ((u32)l[7] << 16));
}

// LDS tile: [rows][32] bf16 (64 B row); XOR-swizzle 16B granules within a row
__device__ __forceinline__ void st_tile16(u16* tile, int row, int kc, uint4 v) {
    int idx = (row * 32 + kc) ^ ((row & 3) << 3);
    *(uint4*)(tile + idx) = v;
}
__device__ __forceinline__ bf16x8 ld_frag(const u16* tile, int row, int ko) {
    int idx = (row * 32 + ko) ^ ((row & 3) << 3);
    return *(const bf16x8*)(tile + idx);
}

// ---------------------------------------------------------------------------
// per-patch class histogram -> Lab bf16 (4,256,1000)
// ---------------------------------------------------------------------------
__global__ __launch_bounds__(256) void patch_hist_kernel(
    const int* __restrict__ labels, u16* __restrict__ label_out)
{
    int bp = blockIdx.x;
    int b = bp >> 8, p = bp & 255;
    int py = p >> 4, px = p & 15;
    __shared__ int hist[NCLS];
    int t = threadIdx.x;
    for (int c = t; c < NCLS; c += 256) hist[c] = 0;
    __syncthreads();
    if (t < PCH * PCH) {
        int dy = t / PCH, dx = t % PCH;
        int y = py * PCH + dy, x = px * PCH + dx;
        int lab = labels[(size_t)b * IMGSZ * IMGSZ + y * IMGSZ + x];
        atomicAdd(&hist[lab], 1);
    }
    __syncthreads();
    const float inv = 1.0f / (PCH * PCH);
    for (int c = t; c < NCLS; c += 256)
        label_out[(size_t)bp * NCLS + c] = f2bf(hist[c] * inv);
}

// ---------------------------------------------------------------------------
// unified MFMA GEMM.  MODE: 0=fc1(+GELU->bf16 hi/lo)  1=fc2(+bias->f32)
//                           2=QK (gathered keys ->f32) 3=PV (bf16 pure ->f32)
// block: 256 thr = 4 waves (2x2), BN=64, BK=32
// ---------------------------------------------------------------------------
template<int MODE>
__global__ __launch_bounds__(256) void gemm_mfma(
    const float* __restrict__ Af, const float* __restrict__ Af2,
    const u16* __restrict__ Ahi_g, const u16* __restrict__ Alo_g,
    const float* __restrict__ Bf,
    const u16* __restrict__ Bhi_g, const u16* __restrict__ Blo_g,
    const float* __restrict__ bias, const int* __restrict__ perms,
    float* __restrict__ Cf, u16* __restrict__ Chi_g, u16* __restrict__ Clo_g)
{
    constexpr int BM    = (MODE == 1) ? 64 : 128;
    constexpr int WM    = BM / 32;                       // m-frags per wave
    constexpr int KDIM  = (MODE == 0 || MODE == 2) ? DIM : (MODE == 1 ? HID : KTOT);
    constexpr bool SPL  = (MODE != 3);                   // hi/lo split?

    __shared__ u16 As_hi[BM * 32];
    __shared__ u16 As_lo[SPL ? BM * 32 : 8];
    __shared__ u16 Bs_hi[64 * 32];
    __shared__ u16 Bs_lo[SPL ? 64 * 32 : 8];
    __shared__ int ap[8];

    const int tid  = threadIdx.x;
    const int lane = tid & 63;
    const int wid  = tid >> 6;
    const int wm   = wid >> 1, wn = wid & 1;
    const int n0   = blockIdx.x * 64;
    const int m0   = blockIdx.y * BM;
    const int b    = blockIdx.z;

    if constexpr (MODE == 2 || MODE == 3) {
        if (tid < 8) ap[tid] = (tid == 0) ? b : perms[(tid - 1) * BSZ + b];
    }

    f32x4 acc[WM][2] = {};

    for (int k0 = 0; k0 < KDIM; k0 += 32) {
        __syncthreads();
        // ---- stage A ----
        if constexpr (MODE == 0) {
            #pragma unroll
            for (int it = 0; it < 2; ++it) {
                int u = tid + it * 256;
                int r = u >> 2, seg = u & 3;
                int gm = m0 + r;
                const float* src = (gm < 1024) ? Af : Af2;
                const float* p = src + (size_t)(gm & 1023) * DIM + k0 + seg * 8;
                float x[8];
                *(float4*)x = *(const float4*)p;
                *(float4*)(x + 4) = *(const float4*)(p + 4);
                uint4 hi, lo; split8(x, hi, lo);
                st_tile16(As_hi, r, seg * 8, hi);
                st_tile16(As_lo, r, seg * 8, lo);
            }
        } else if constexpr (MODE == 1) {
            int r = tid >> 2, seg = tid & 3;
            size_t off = (size_t)(m0 + r) * HID + k0 + seg * 8;
            st_tile16(As_hi, r, seg * 8, *(const uint4*)(Ahi_g + off));
            st_tile16(As_lo, r, seg * 8, *(const uint4*)(Alo_g + off));
        } else if constexpr (MODE == 2) {
            #pragma unroll
            for (int it = 0; it < 2; ++it) {
                int u = tid + it * 256;
                int r = u >> 2, seg = u & 3;
                size_t off = (size_t)(b * NPATCH + m0 + r) * DIM + k0 + seg * 8;
                st_tile16(As_hi, r, seg * 8, *(const uint4*)(Ahi_g + off));
                st_tile16(As_lo, r, seg * 8, *(const uint4*)(Alo_g + off));
            }
        } else {
            #pragma unroll
            for (int it = 0; it < 2; ++it) {
                int u = tid + it * 256;
                int r = u >> 2, seg = u & 3;
                size_t off = (size_t)(b * NPATCH + m0 + r) * KTOT + k0 + seg * 8;
                st_tile16(As_hi, r, seg * 8, *(const uint4*)(Ahi_g + off));
            }
        }
        // ---- stage B ----
        if constexpr (MODE == 0 || MODE == 1) {
            constexpr int N = (MODE == 0) ? HID : DIM;
            int n = tid & 63, kc = (tid >> 6) * 8;
            const float* p = Bf + (size_t)(k0 + kc) * N + n0 + n;
            float x[8];
            #pragma unroll
            for (int j = 0; j < 8; ++j) x[j] = p[(size_t)j * N];
            uint4 hi, lo; split8(x, hi, lo);
            st_tile16(Bs_hi, n, kc, hi);
            st_tile16(Bs_lo, n, kc, lo);
        } else if constexpr (MODE == 2) {
            int n = tid >> 2, seg = tid & 3;
            int kg = n0 + n;
            int srcr = ap[kg >> 8] * NPATCH + (kg & 255);
            size_t off = (size_t)(1024 + srcr) * DIM + k0 + seg * 8;
            st_tile16(Bs_hi, n, seg * 8, *(const uint4*)(Bhi_g + off));
            st_tile16(Bs_lo, n, seg * 8, *(const uint4*)(Blo_g + off));
        } else {
            int n = tid & 63, kc = (tid >> 6) * 8;
            int gn = n0 + n;
            u16 x[8];
            #pragma unroll
            for (int j = 0; j < 8; ++j) {
                int kg = k0 + kc + j;
                int srcr = ap[kg >> 8] * NPATCH + (kg & 255);
                x[j] = (gn < NCLS) ? Bhi_g[(size_t)srcr * NCLS + gn] : (u16)0;
            }
            st_tile16(Bs_hi, n, kc, *(const uint4*)x);
        }
        __syncthreads();
        // ---- compute ----
        const int arow = wm * (WM * 16) + (lane & 15);
        const int brow = wn * 32 + (lane & 15);
        const int ko = (lane >> 4) * 8;
        bf16x8 a_hi[WM], a_lo[WM], b_hi[2], b_lo[2];
        #pragma unroll
        for (int mi = 0; mi < WM; ++mi) {
            a_hi[mi] = ld_frag(As_hi, arow + 16 * mi, ko);
            if constexpr (SPL) a_lo[mi] = ld_frag(As_lo, arow + 16 * mi, ko);
        }
        #pragma unroll
        for (int ni = 0; ni < 2; ++ni) {
            b_hi[ni] = ld_frag(Bs_hi, brow + 16 * ni, ko);
            if constexpr (SPL) b_lo[ni] = ld_frag(Bs_lo, brow + 16 * ni, ko);
        }
        #pragma unroll
        for (int mi = 0; mi < WM; ++mi)
            #pragma unroll
            for (int ni = 0; ni < 2; ++ni) {
                acc[mi][ni] = __builtin_amdgcn_mfma_f32_16x16x32_bf16(
                    a_hi[mi], b_hi[ni], acc[mi][ni], 0, 0, 0);
                if constexpr (SPL) {
                    acc[mi][ni] = __builtin_amdgcn_mfma_f32_16x16x32_bf16(
                        a_hi[mi], b_lo[ni], acc[mi][ni], 0, 0, 0);
                    acc[mi][ni] = __builtin_amdgcn_mfma_f32_16x16x32_bf16(
                        a_lo[mi], b_hi[ni], acc[mi][ni], 0, 0, 0);
                }
            }
    }

    // ---- epilogue ----
    #pragma unroll
    for (int mi = 0; mi < WM; ++mi)
        #pragma unroll
        for (int ni = 0; ni < 2; ++ni)
            #pragma unroll
            for (int r = 0; r < 4; ++r) {
                int gm = m0 + wm * (WM * 16) + mi * 16 + ((lane >> 4) << 2) + r;
                int gn = n0 + wn * 32 + ni * 16 + (lane & 15);
                float v = acc[mi][ni][r];
                if constexpr (MODE == 0) {
                    v += bias[gn];
                    v = 0.5f * v * (1.0f + erff(v * 0.7071067811865476f));
                    u16 h = f2bf(v);
                    Chi_g[(size_t)gm * HID + gn] = h;
                    Clo_g[(size_t)gm * HID + gn] = f2bf(v - bf2f(h));
                } else if constexpr (MODE == 1) {
                    Cf[(size_t)gm * DIM + gn] = v + bias[gn];
                } else if constexpr (MODE == 2) {
                    Cf[((size_t)b * NPATCH + gm) * KTOT + gn] = v;
                } else {
                    if (gn < NCLS)
                        Cf[((size_t)b * NPATCH + gm) * NCLS + gn] = v;
                }
            }
}

// ---------------------------------------------------------------------------
// LayerNorm + L2 norm -> Zhi/Zlo bf16 split
// ---------------------------------------------------------------------------
__device__ __forceinline__ float wave_sum(float v) {
    #pragma unroll
    for (int off = 32; off > 0; off >>= 1) v += __shfl_xor(v, off);
    return v;
}

__global__ __launch_bounds__(256) void ln_l2_kernel(
    const float* __restrict__ Yp, const float* __restrict__ w,
    const float* __restrict__ b, u16* __restrict__ Zhi, u16* __restrict__ Zlo)
{
    int wid = threadIdx.x >> 6, lane = threadIdx.x & 63;
    int row = blockIdx.x * 4 + wid;
    const float* y = Yp + (size_t)row * DIM;
    float x[6];
    float s = 0.0f;
    #pragma unroll
    for (int i = 0; i < 6; ++i) { x[i] = y[lane + 64 * i]; s += x[i]; }
    s = wave_sum(s);
    float mu = s * (1.0f / DIM);
    float vs = 0.0f;
    #pragma unroll
    for (int i = 0; i < 6; ++i) { float d = x[i] - mu; vs += d * d; }
    vs = wave_sum(vs);
    float rstd = 1.0f / sqrtf(vs * (1.0f / DIM) + LN_EPS_F);
    float z[6];
    float n2 = 0.0f;
    #pragma unroll
    for (int i = 0; i < 6; ++i) {
        z[i] = (x[i] - mu) * rstd * w[lane + 64 * i] + b[lane + 64 * i];
        n2 += z[i] * z[i];
    }
    n2 = wave_sum(n2);
    float inv = 1.0f / fmaxf(sqrtf(n2), 1e-12f);
    #pragma unroll
    for (int i = 0; i < 6; ++i) {
        float zn = z[i] * inv;
        u16 h = f2bf(zn);
        Zhi[(size_t)row * DIM + lane + 64 * i] = h;
        Zlo[(size_t)row * DIM + lane + 64 * i] = f2bf(zn - bf2f(h));
    }
}

// ---------------------------------------------------------------------------
// row softmax (2048, scaled 1/beta): S f32 -> Attn bf16
// ---------------------------------------------------------------------------
__global__ __launch_bounds__(256) void softmax_kernel(
    const float* __restrict__ S, u16* __restrict__ A)
{
    int row = blockIdx.x;
    const float* p = S + (size_t)row * KTOT;
    int t = threadIdx.x;
    float v[8];
    float m = -1e30f;
    #pragma unroll
    for (int i = 0; i < 8; ++i) {
        v[i] = p[t + 256 * i] * INV_BETA;
        m = fmaxf(m, v[i]);
    }
    #pragma unroll
    for (int off = 32; off > 0; off >>= 1) m = fmaxf(m, __shfl_xor(m, off));
    __shared__ float redm[4];
    __shared__ float reds[4];
    int wid = t >> 6;
    if ((t & 63) == 0) redm[wid] = m;
    __syncthreads();
    m = fmaxf(fmaxf(redm[0], redm[1]), fmaxf(redm[2], redm[3]));
    float s = 0.0f;
    #pragma unroll
    for (int i = 0; i < 8; ++i) { v[i] = expf(v[i] - m); s += v[i]; }
    s = wave_sum(s);
    if ((t & 63) == 0) reds[wid] = s;
    __syncthreads();
    s = reds[0] + reds[1] + reds[2] + reds[3];
    float inv = 1.0f / s;
    u16* q = A + (size_t)row * KTOT;
    #pragma unroll
    for (int i = 0; i < 8; ++i) q[t + 256 * i] = f2bf(v[i] * inv);
}

// ---------------------------------------------------------------------------
// nearest-upsample 16x16 -> 224x224 with (q,c)->(c,y,x) transpose
// ---------------------------------------------------------------------------
__global__ __launch_bounds__(256) void upsample_kernel(
    const float* __restrict__ Lhat, float* __restrict__ out)
{
    int blk = blockIdx.x;
    int gy = blk & 15;
    int bc = blk >> 4;
    int c = bc % NCLS;
    int b = bc / NCLS;
    __shared__ float vals[GRD];
    int t = threadIdx.x;
    if (t < GRD)
        vals[t] = Lhat[((size_t)(b * NPATCH + gy * GRD + t)) * NCLS + c];
    __syncthreads();
    float* obase = out + ((size_t)(b * NCLS + c) * IMGSZ + gy * PCH) * IMGSZ;
    for (int idx = t; idx < PCH * 56; idx += 256) {
        int x4 = idx % 56, dy = idx / 56;
        int x0 = x4 * 4;
        float4 v = make_float4(vals[x0 / PCH], vals[(x0 + 1) / PCH],
                               vals[(x0 + 2) / PCH], vals[(x0 + 3) / PCH]);
        *(float4*)(obase + dy * IMGSZ + x0) = v;
    }
}

// ---------------------------------------------------------------------------
extern "C" void kernel_launch(void* const* d_in, const int* in_sizes, int n_in,
                              void* d_out, int out_size, void* d_ws, size_t ws_size,
                              hipStream_t stream)
{
    (void)in_sizes; (void)n_in; (void)out_size; (void)ws_size;
    const float* feat_t = (const float*)d_in[0];
    const float* feat_r = (const float*)d_in[1];
    const int*   labels = (const int*)d_in[2];
    const int*   perms  = (const int*)d_in[3];
    const float* fc1_w  = (const float*)d_in[4];
    const float* fc1_b  = (const float*)d_in[5];
    const float* fc2_w  = (const float*)d_in[6];
    const float* fc2_b  = (const float*)d_in[7];
    const float* ln_w   = (const float*)d_in[8];
    const float* ln_b   = (const float*)d_in[9];
    float* out = (float*)d_out;
    char*  W   = (char*)d_ws;

    // region 1 (22,020,096 B): Hhi/Hlo, later reused for S/Attn/Lhat
    u16*   Hhi  = (u16*)(W + 0);
    u16*   Hlo  = (u16*)(W + 11010048);
    float* S    = (float*)(W + 0);
    u16*   Attn = (u16*)(W + 8388608);
    float* Lhat = (float*)(W + 12582912);
    // region 2
    float* Yp   = (float*)(W + 22020096);
    u16*   Zhi  = (u16*)(W + 25165824);
    u16*   Zlo  = (u16*)(W + 26738688);
    u16*   Lab  = (u16*)(W + 28311552);

    patch_hist_kernel<<<dim3(BSZ * NPATCH), dim3(256), 0, stream>>>(labels, Lab);

    gemm_mfma<0><<<dim3(HID / 64, 2048 / 128), dim3(256), 0, stream>>>(
        feat_t, feat_r, nullptr, nullptr, fc1_w, nullptr, nullptr,
        fc1_b, nullptr, nullptr, Hhi, Hlo);

    gemm_mfma<1><<<dim3(DIM / 64, 2048 / 64), dim3(256), 0, stream>>>(
        nullptr, nullptr, Hhi, Hlo, fc2_w, nullptr, nullptr,
        fc2_b, nullptr, Yp, nullptr, nullptr);

    ln_l2_kernel<<<dim3(2048 / 4), dim3(256), 0, stream>>>(Yp, ln_w, ln_b, Zhi, Zlo);

    gemm_mfma<2><<<dim3(KTOT / 64, NPATCH / 128, BSZ), dim3(256), 0, stream>>>(
        nullptr, nullptr, Zhi, Zlo, nullptr, Zhi, Zlo,
        nullptr, perms, S, nullptr, nullptr);

    softmax_kernel<<<dim3(BSZ * NPATCH), dim3(256), 0, stream>>>(S, Attn);

    gemm_mfma<3><<<dim3(16, NPATCH / 128, BSZ), dim3(256), 0, stream>>>(
        nullptr, nullptr, Attn, nullptr, nullptr, Lab, nullptr,
        nullptr, perms, Lhat, nullptr, nullptr);

    upsample_kernel<<<dim3(BSZ * NCLS * GRD), dim3(256), 0, stream>>>(Lhat, out);
}

// Round 3
// 335.219 us; speedup vs baseline: 1.8773x; 1.2147x over previous
//
#include <hip/hip_runtime.h>

#define BSZ 4
#define NPATCH 256
#define DIM 384
#define HID 2688
#define NCLS 1000
#define KTOT 2048
#define IMGSZ 224
#define PCH 14
#define GRD 16

static constexpr float INV_BETA = 1.0f / 0.07f;
static constexpr float LN_EPS_F = 1e-6f;

typedef unsigned short u16;
typedef unsigned int   u32;
typedef __attribute__((ext_vector_type(8))) __bf16 bf16x8;
typedef __attribute__((ext_vector_type(4))) float  f32x4;

__device__ __forceinline__ u16 f2bf(float f) {
    u32 u = __float_as_uint(f);
    return (u16)((u + 0x7FFFu + ((u >> 16) & 1u)) >> 16);
}
__device__ __forceinline__ float bf2f(u16 h) {
    return __uint_as_float(((u32)h) << 16);
}
__device__ __forceinline__ f32x4 mfma16(bf16x8 a, bf16x8 b, f32x4 c) {
    return __builtin_amdgcn_mfma_f32_16x16x32_bf16(a, b, c, 0, 0, 0);
}
// async global->LDS, 16B per lane, linear LDS dest (wave-uniform base + lane*16)
__device__ __forceinline__ void gll16(const u16* g, u16* l) {
    __builtin_amdgcn_global_load_lds(
        (const __attribute__((address_space(1))) void*)g,
        (__attribute__((address_space(3))) void*)l, 16, 0, 0);
}
__device__ __forceinline__ bf16x8 ld8(const u16* p) {
    return *(const bf16x8*)p;
}

// ---------------------------------------------------------------------------
// split feat_t/feat_r (f32) -> X hi/lo bf16 [2048][384]
// ---------------------------------------------------------------------------
__global__ __launch_bounds__(256) void split_feat_kernel(
    const float* __restrict__ Xt, const float* __restrict__ Xr,
    u16* __restrict__ Xhi, u16* __restrict__ Xlo)
{
    int e = (blockIdx.x * 256 + threadIdx.x) * 4;      // 786432 total
    const float* src = (e < 1024 * DIM) ? (Xt + e) : (Xr + e - 1024 * DIM);
    float4 v = *(const float4*)src;
    float x[4] = {v.x, v.y, v.z, v.w};
    u16 h[4], l[4];
    #pragma unroll
    for (int i = 0; i < 4; ++i) {
        h[i] = f2bf(x[i]);
        l[i] = f2bf(x[i] - bf2f(h[i]));
    }
    *(uint2*)(Xhi + e) = make_uint2((u32)h[0] | ((u32)h[1] << 16), (u32)h[2] | ((u32)h[3] << 16));
    *(uint2*)(Xlo + e) = make_uint2((u32)l[0] | ((u32)l[1] << 16), (u32)l[2] | ((u32)l[3] << 16));
}

// ---------------------------------------------------------------------------
// transpose + split: In f32 [R][C] -> OutHi/OutLo bf16 [C][R]
// ---------------------------------------------------------------------------
__global__ __launch_bounds__(256) void transpose_split_kernel(
    const float* __restrict__ In, int R, int C,
    u16* __restrict__ OutHi, u16* __restrict__ OutLo)
{
    __shared__ float tile[32][33];
    int cx = blockIdx.x * 32, ry = blockIdx.y * 32;
    int tr = threadIdx.x >> 5, tc = threadIdx.x & 31;
    #pragma unroll
    for (int i = 0; i < 4; ++i)
        tile[tr + i * 8][tc] = In[(size_t)(ry + tr + i * 8) * C + cx + tc];
    __syncthreads();
    #pragma unroll
    for (int i = 0; i < 4; ++i) {
        int orow = cx + tr + i * 8;
        int ocol = ry + tc;
        float v = tile[tc][tr + i * 8];
        u16 h = f2bf(v);
        OutHi[(size_t)orow * R + ocol] = h;
        OutLo[(size_t)orow * R + ocol] = f2bf(v - bf2f(h));
    }
}

// ---------------------------------------------------------------------------
// per-patch class histogram -> LabT bf16 [4][1000][256]  (class-major!)
// ---------------------------------------------------------------------------
__global__ __launch_bounds__(256) void patch_hist_kernel(
    const int* __restrict__ labels, u16* __restrict__ LabT)
{
    int bp = blockIdx.x;
    int b = bp >> 8, p = bp & 255;
    int py = p >> 4, px = p & 15;
    __shared__ int hist[NCLS];
    int t = threadIdx.x;
    for (int c = t; c < NCLS; c += 256) hist[c] = 0;
    __syncthreads();
    if (t < PCH * PCH) {
        int dy = t / PCH, dx = t % PCH;
        int y = py * PCH + dy, x = px * PCH + dx;
        int lab = labels[(size_t)b * IMGSZ * IMGSZ + y * IMGSZ + x];
        atomicAdd(&hist[lab], 1);
    }
    __syncthreads();
    const float inv = 1.0f / (PCH * PCH);
    for (int c = t; c < NCLS; c += 256)
        LabT[((size_t)b * NCLS + c) * 256 + p] = f2bf(hist[c] * inv);
}

// ---------------------------------------------------------------------------
// MLP GEMM (NT, hi/lo 3-MFMA): 128x64 tile, BK=32, 8 waves (4m x 2n, 32x32),
// double-buffered LDS via global_load_lds, 1 barrier / K-step.
// MODE 0: fc1  X[2048][384] * W1T[2688][384] + b -> GELU -> Hhi/Hlo
// MODE 1: fc2  H[2048][2688] * W2T[384][2688] -> f32 partial (split-K via z)
// ---------------------------------------------------------------------------
template<int MODE>
__global__ __launch_bounds__(512) void mlp_gemm(
    const u16* __restrict__ Ahi, const u16* __restrict__ Alo,
    const u16* __restrict__ Bhi, const u16* __restrict__ Blo,
    const float* __restrict__ bias,
    u16* __restrict__ OutHi, u16* __restrict__ OutLo, float* __restrict__ OutF)
{
    constexpr int K  = (MODE == 0) ? DIM : HID;
    constexpr int KS = (MODE == 0) ? DIM : HID / 2;
    constexpr int NT = KS / 32;
    constexpr int N  = (MODE == 0) ? HID : DIM;

    __shared__ u16 As_h[2][128 * 32];
    __shared__ u16 As_l[2][128 * 32];
    __shared__ u16 Bs_h[2][64 * 32];
    __shared__ u16 Bs_l[2][64 * 32];

    const int tid  = threadIdx.x;
    const int lane = tid & 63, wid = tid >> 6;
    const int wm = wid >> 1, wn = wid & 1;
    const int n0 = blockIdx.x * 64, m0 = blockIdx.y * 128;
    const int kbase = (MODE == 1) ? blockIdx.z * KS : 0;

    const u16* a_h = Ahi + (size_t)m0 * K + kbase;
    const u16* a_l = Alo + (size_t)m0 * K + kbase;
    const u16* b_h = Bhi + (size_t)n0 * K + kbase;
    const u16* b_l = Blo + (size_t)n0 * K + kbase;

    const int ar = tid >> 2, ac = (tid & 3) * 8;           // A: 512 chunks
    const int ub = tid & 255;
    const int br = ub >> 2, bc2 = (ub & 3) * 8;            // B: 256 chunks x2

    auto stage = [&](int buf, int k0) {
        gll16(a_h + (size_t)ar * K + k0 + ac, &As_h[buf][tid * 8]);
        gll16(a_l + (size_t)ar * K + k0 + ac, &As_l[buf][tid * 8]);
        if (tid < 256) gll16(b_h + (size_t)br * K + k0 + bc2, &Bs_h[buf][ub * 8]);
        else           gll16(b_l + (size_t)br * K + k0 + bc2, &Bs_l[buf][ub * 8]);
    };

    const int l15 = lane & 15, q8 = (lane >> 4) * 8;
    const int arow = wm * 32 + l15;
    const int brow = wn * 32 + l15;

    f32x4 acc[2][2] = {};

    int cur = 0;
    stage(0, 0);
    asm volatile("s_waitcnt vmcnt(0)" ::: "memory");
    __syncthreads();
    for (int t = 0; t < NT; ++t) {
        if (t + 1 < NT) stage(cur ^ 1, (t + 1) * 32);
        bf16x8 ah[2], al[2], bh[2], bl[2];
        #pragma unroll
        for (int mi = 0; mi < 2; ++mi) {
            ah[mi] = ld8(&As_h[cur][(arow + mi * 16) * 32 + q8]);
            al[mi] = ld8(&As_l[cur][(arow + mi * 16) * 32 + q8]);
        }
        #pragma unroll
        for (int ni = 0; ni < 2; ++ni) {
            bh[ni] = ld8(&Bs_h[cur][(brow + ni * 16) * 32 + q8]);
            bl[ni] = ld8(&Bs_l[cur][(brow + ni * 16) * 32 + q8]);
        }
        #pragma unroll
        for (int mi = 0; mi < 2; ++mi)
            #pragma unroll
            for (int ni = 0; ni < 2; ++ni) {
                acc[mi][ni] = mfma16(ah[mi], bh[ni], acc[mi][ni]);
                acc[mi][ni] = mfma16(ah[mi], bl[ni], acc[mi][ni]);
                acc[mi][ni] = mfma16(al[mi], bh[ni], acc[mi][ni]);
            }
        asm volatile("s_waitcnt vmcnt(0)" ::: "memory");
        __syncthreads();
        cur ^= 1;
    }

    #pragma unroll
    for (int mi = 0; mi < 2; ++mi)
        #pragma unroll
        for (int ni = 0; ni < 2; ++ni)
            #pragma unroll
            for (int r = 0; r < 4; ++r) {
                int gm = m0 + wm * 32 + mi * 16 + ((lane >> 4) << 2) + r;
                int gn = n0 + wn * 32 + ni * 16 + l15;
                float v = acc[mi][ni][r];
                if constexpr (MODE == 0) {
                    v += bias[gn];
                    v = 0.5f * v * (1.0f + erff(v * 0.7071067811865476f));
                    u16 h = f2bf(v);
                    OutHi[(size_t)gm * N + gn] = h;
                    OutLo[(size_t)gm * N + gn] = f2bf(v - bf2f(h));
                } else {
                    OutF[(size_t)blockIdx.z * (2048 * DIM) + (size_t)gm * N + gn] = v;
                }
            }
}

// ---------------------------------------------------------------------------
// split-K reduce + bias + LayerNorm + L2 norm -> Zhi/Zlo; one wave per row
// ---------------------------------------------------------------------------
__device__ __forceinline__ float wave_sum(float v) {
    #pragma unroll
    for (int off = 32; off > 0; off >>= 1) v += __shfl_xor(v, off);
    return v;
}

__global__ __launch_bounds__(256) void ln_l2_kernel(
    const float* __restrict__ P0, const float* __restrict__ fc2b,
    const float* __restrict__ w, const float* __restrict__ b,
    u16* __restrict__ Zhi, u16* __restrict__ Zlo)
{
    const float* P1 = P0 + 2048 * DIM;
    int wid = threadIdx.x >> 6, lane = threadIdx.x & 63;
    int row = blockIdx.x * 4 + wid;
    size_t base = (size_t)row * DIM;
    float x[6];
    float s = 0.0f;
    #pragma unroll
    for (int i = 0; i < 6; ++i) {
        int c = lane + 64 * i;
        x[i] = P0[base + c] + P1[base + c] + fc2b[c];
        s += x[i];
    }
    s = wave_sum(s);
    float mu = s * (1.0f / DIM);
    float vs = 0.0f;
    #pragma unroll
    for (int i = 0; i < 6; ++i) { float d = x[i] - mu; vs += d * d; }
    vs = wave_sum(vs);
    float rstd = 1.0f / sqrtf(vs * (1.0f / DIM) + LN_EPS_F);
    float z[6];
    float n2 = 0.0f;
    #pragma unroll
    for (int i = 0; i < 6; ++i) {
        z[i] = (x[i] - mu) * rstd * w[lane + 64 * i] + b[lane + 64 * i];
        n2 += z[i] * z[i];
    }
    n2 = wave_sum(n2);
    float inv = 1.0f / fmaxf(sqrtf(n2), 1e-12f);
    #pragma unroll
    for (int i = 0; i < 6; ++i) {
        float zn = z[i] * inv;
        u16 h = f2bf(zn);
        Zhi[base + lane + 64 * i] = h;
        Zlo[base + lane + 64 * i] = f2bf(zn - bf2f(h));
    }
}

// ---------------------------------------------------------------------------
// QK^T, no LDS (L2-resident operands): 64x128 tile, 8 waves (2m x 4n, 32x32)
// hi/lo 3-MFMA.  S[b][256][2048] f32
// ---------------------------------------------------------------------------
__global__ __launch_bounds__(512) void qk_kernel(
    const u16* __restrict__ Zhi, const u16* __restrict__ Zlo,
    const int* __restrict__ perms, float* __restrict__ S)
{
    const int tid = threadIdx.x, lane = tid & 63, wid = tid >> 6;
    const int wm = wid >> 2, wn = wid & 3;
    const int n0 = blockIdx.x * 128, m0 = blockIdx.y * 64, b = blockIdx.z;
    const int d = n0 >> 8;
    const int apd = (d == 0) ? b : perms[(d - 1) * BSZ + b];
    const int l15 = lane & 15, q8 = (lane >> 4) * 8;
    const size_t mrow0 = (size_t)(b * 256 + m0 + wm * 32 + l15) * DIM;
    const size_t krow0 = (size_t)(1024 + apd * 256 + (n0 & 255) + wn * 32 + l15) * DIM;

    f32x4 acc[2][2] = {};
    #pragma unroll 2
    for (int k0 = 0; k0 < DIM; k0 += 32) {
        bf16x8 ah[2], al[2], bh[2], bl[2];
        #pragma unroll
        for (int mi = 0; mi < 2; ++mi) {
            ah[mi] = ld8(Zhi + mrow0 + (size_t)mi * 16 * DIM + k0 + q8);
            al[mi] = ld8(Zlo + mrow0 + (size_t)mi * 16 * DIM + k0 + q8);
        }
        #pragma unroll
        for (int ni = 0; ni < 2; ++ni) {
            bh[ni] = ld8(Zhi + krow0 + (size_t)ni * 16 * DIM + k0 + q8);
            bl[ni] = ld8(Zlo + krow0 + (size_t)ni * 16 * DIM + k0 + q8);
        }
        #pragma unroll
        for (int mi = 0; mi < 2; ++mi)
            #pragma unroll
            for (int ni = 0; ni < 2; ++ni) {
                acc[mi][ni] = mfma16(ah[mi], bh[ni], acc[mi][ni]);
                acc[mi][ni] = mfma16(ah[mi], bl[ni], acc[mi][ni]);
                acc[mi][ni] = mfma16(al[mi], bh[ni], acc[mi][ni]);
            }
    }
    #pragma unroll
    for (int mi = 0; mi < 2; ++mi)
        #pragma unroll
        for (int ni = 0; ni < 2; ++ni)
            #pragma unroll
            for (int r = 0; r < 4; ++r) {
                int gm = m0 + wm * 32 + mi * 16 + ((lane >> 4) << 2) + r;
                int gn = n0 + wn * 32 + ni * 16 + l15;
                S[((size_t)b * 256 + gm) * KTOT + gn] = acc[mi][ni][r];
            }
}

// ---------------------------------------------------------------------------
// row softmax (2048, 1/beta): S f32 -> Attn bf16
// ---------------------------------------------------------------------------
__global__ __launch_bounds__(256) void softmax_kernel(
    const float* __restrict__ S, u16* __restrict__ A)
{
    int row = blockIdx.x;
    const float* p = S + (size_t)row * KTOT;
    int t = threadIdx.x;
    float v[8];
    float m = -1e30f;
    #pragma unroll
    for (int i = 0; i < 8; ++i) {
        v[i] = p[t + 256 * i] * INV_BETA;
        m = fmaxf(m, v[i]);
    }
    #pragma unroll
    for (int off = 32; off > 0; off >>= 1) m = fmaxf(m, __shfl_xor(m, off));
    __shared__ float redm[4];
    __shared__ float reds[4];
    int wid = t >> 6;
    if ((t & 63) == 0) redm[wid] = m;
    __syncthreads();
    m = fmaxf(fmaxf(redm[0], redm[1]), fmaxf(redm[2], redm[3]));
    float s = 0.0f;
    #pragma unroll
    for (int i = 0; i < 8; ++i) { v[i] = expf(v[i] - m); s += v[i]; }
    s = wave_sum(s);
    if ((t & 63) == 0) reds[wid] = s;
    __syncthreads();
    s = reds[0] + reds[1] + reds[2] + reds[3];
    float inv = 1.0f / s;
    u16* q = A + (size_t)row * KTOT;
    #pragma unroll
    for (int i = 0; i < 8; ++i) q[t + 256 * i] = f2bf(v[i] * inv);
}

// ---------------------------------------------------------------------------
// PV, no LDS: Attn[b][256][2048] bf16 * LabT-gather -> Lhat f32 [b][256][1000]
// 64x64 tile, 8 waves (2m x 4n, 32x16)
// ---------------------------------------------------------------------------
__global__ __launch_bounds__(512) void pv_kernel(
    const u16* __restrict__ Attn, const u16* __restrict__ LabT,
    const int* __restrict__ perms, float* __restrict__ Lhat)
{
    const int tid = threadIdx.x, lane = tid & 63, wid = tid >> 6;
    const int wm = wid >> 2, wn = wid & 3;
    const int n0 = blockIdx.x * 64, m0 = blockIdx.y * 64, b = blockIdx.z;
    const int l15 = lane & 15, q8 = (lane >> 4) * 8;
    const int gn = n0 + wn * 16 + l15;
    const int cc = (gn < NCLS) ? gn : (NCLS - 1);
    const size_t arow0 = (size_t)(b * 256 + m0 + wm * 32 + l15) * KTOT;

    f32x4 acc[2] = {};
    for (int s = 0; s < 8; ++s) {
        int apd = (s == 0) ? b : perms[(s - 1) * BSZ + b];
        const u16* bptr = LabT + ((size_t)apd * NCLS + cc) * 256;
        const u16* aptr = Attn + arow0 + s * 256;
        #pragma unroll 4
        for (int t8 = 0; t8 < 8; ++t8) {
            int p = t8 * 32 + q8;
            bf16x8 bf = ld8(bptr + p);
            #pragma unroll
            for (int mi = 0; mi < 2; ++mi) {
                bf16x8 af = ld8(aptr + (size_t)mi * 16 * KTOT + p);
                acc[mi] = mfma16(af, bf, acc[mi]);
            }
        }
    }
    if (gn < NCLS) {
        #pragma unroll
        for (int mi = 0; mi < 2; ++mi)
            #pragma unroll
            for (int r = 0; r < 4; ++r) {
                int gm = m0 + wm * 32 + mi * 16 + ((lane >> 4) << 2) + r;
                Lhat[((size_t)b * 256 + gm) * NCLS + gn] = acc[mi][r];
            }
    }
}

// ---------------------------------------------------------------------------
// nearest-upsample 16x16 -> 224x224 with (q,c)->(c,y,x) transpose
// ---------------------------------------------------------------------------
__global__ __launch_bounds__(256) void upsample_kernel(
    const float* __restrict__ Lhat, float* __restrict__ out)
{
    int blk = blockIdx.x;
    int gy = blk & 15;
    int bc = blk >> 4;
    int c = bc % NCLS;
    int b = bc / NCLS;
    __shared__ float vals[GRD];
    int t = threadIdx.x;
    if (t < GRD)
        vals[t] = Lhat[((size_t)(b * NPATCH + gy * GRD + t)) * NCLS + c];
    __syncthreads();
    float* obase = out + ((size_t)(b * NCLS + c) * IMGSZ + gy * PCH) * IMGSZ;
    for (int idx = t; idx < PCH * 56; idx += 256) {
        int x4 = idx % 56, dy = idx / 56;
        int x0 = x4 * 4;
        float4 v = make_float4(vals[x0 / PCH], vals[(x0 + 1) / PCH],
                               vals[(x0 + 2) / PCH], vals[(x0 + 3) / PCH]);
        *(float4*)(obase + dy * IMGSZ + x0) = v;
    }
}

// ---------------------------------------------------------------------------
extern "C" void kernel_launch(void* const* d_in, const int* in_sizes, int n_in,
                              void* d_out, int out_size, void* d_ws, size_t ws_size,
                              hipStream_t stream)
{
    (void)in_sizes; (void)n_in; (void)out_size; (void)ws_size;
    const float* feat_t = (const float*)d_in[0];
    const float* feat_r = (const float*)d_in[1];
    const int*   labels = (const int*)d_in[2];
    const int*   perms  = (const int*)d_in[3];
    const float* fc1_w  = (const float*)d_in[4];
    const float* fc1_b  = (const float*)d_in[5];
    const float* fc2_w  = (const float*)d_in[6];
    const float* fc2_b  = (const float*)d_in[7];
    const float* ln_w   = (const float*)d_in[8];
    const float* ln_b   = (const float*)d_in[9];
    float* out = (float*)d_out;
    char*  W   = (char*)d_ws;

    // workspace layout (bytes)
    u16*   Hhi  = (u16*)(W + 0);            // 11,010,048
    u16*   Hlo  = (u16*)(W + 11010048);     // -> 22,020,096
    float* S    = (float*)(W + 0);          // 8,388,608 (aliases H, post-fc2)
    u16*   Attn = (u16*)(W + 8388608);      // 4,194,304
    float* Lhat = (float*)(W + 12582912);   // 4,096,000
    float* P0   = (float*)(W + 22020096);   // 2 x 3,145,728 (split-K partials)
    u16*   Zhi  = (u16*)(W + 28311552);     // 1,572,864
    u16*   Zlo  = (u16*)(W + 29884416);     // 1,572,864
    u16*   LabT = (u16*)(W + 31457280);     // 2,048,000
    u16*   Xhi  = (u16*)(W + 33505536);     // 1,572,864
    u16*   Xlo  = (u16*)(W + 35078400);     // 1,572,864
    u16*   W1Th = (u16*)(W + 36651264);     // 2,064,384
    u16*   W1Tl = (u16*)(W + 38715648);     // 2,064,384
    u16*   W2Th = (u16*)(W + 40780032);     // 2,064,384
    u16*   W2Tl = (u16*)(W + 42844416);     // 2,064,384

    split_feat_kernel<<<dim3(768), dim3(256), 0, stream>>>(feat_t, feat_r, Xhi, Xlo);
    transpose_split_kernel<<<dim3(HID / 32, DIM / 32), dim3(256), 0, stream>>>(
        fc1_w, DIM, HID, W1Th, W1Tl);
    transpose_split_kernel<<<dim3(DIM / 32, HID / 32), dim3(256), 0, stream>>>(
        fc2_w, HID, DIM, W2Th, W2Tl);
    patch_hist_kernel<<<dim3(BSZ * NPATCH), dim3(256), 0, stream>>>(labels, LabT);

    mlp_gemm<0><<<dim3(HID / 64, 2048 / 128), dim3(512), 0, stream>>>(
        Xhi, Xlo, W1Th, W1Tl, fc1_b, Hhi, Hlo, nullptr);

    mlp_gemm<1><<<dim3(DIM / 64, 2048 / 128, 2), dim3(512), 0, stream>>>(
        Hhi, Hlo, W2Th, W2Tl, nullptr, nullptr, nullptr, P0);

    ln_l2_kernel<<<dim3(2048 / 4), dim3(256), 0, stream>>>(P0, fc2_b, ln_w, ln_b, Zhi, Zlo);

    qk_kernel<<<dim3(KTOT / 128, NPATCH / 64, BSZ), dim3(512), 0, stream>>>(
        Zhi, Zlo, perms, S);

    softmax_kernel<<<dim3(BSZ * NPATCH), dim3(256), 0, stream>>>(S, Attn);

    pv_kernel<<<dim3(16, NPATCH / 64, BSZ), dim3(512), 0, stream>>>(
        Attn, LabT, perms, Lhat);

    upsample_kernel<<<dim3(BSZ * NCLS * GRD), dim3(256), 0, stream>>>(Lhat, out);
}

// Round 4
// 290.980 us; speedup vs baseline: 2.1628x; 1.1520x over previous
//
#include <hip/hip_runtime.h>

#define BSZ 4
#define NPATCH 256
#define DIM 384
#define HID 2688
#define NCLS 1000
#define CPAD 1024
#define KTOT 2048
#define IMGSZ 224
#define PCH 14
#define GRD 16

static constexpr float INV_BETA = 1.0f / 0.07f;
static constexpr float LN_EPS_F = 1e-6f;

typedef unsigned short u16;
typedef unsigned int   u32;
typedef __attribute__((ext_vector_type(8))) __bf16 bf16x8;
typedef __attribute__((ext_vector_type(4))) float  f32x4;

__device__ __forceinline__ u16 f2bf(float f) {
    u32 u = __float_as_uint(f);
    return (u16)((u + 0x7FFFu + ((u >> 16) & 1u)) >> 16);
}
__device__ __forceinline__ float bf2f(u16 h) {
    return __uint_as_float(((u32)h) << 16);
}
__device__ __forceinline__ f32x4 mfma16(bf16x8 a, bf16x8 b, f32x4 c) {
    return __builtin_amdgcn_mfma_f32_16x16x32_bf16(a, b, c, 0, 0, 0);
}
// async global->LDS, 16B/lane, linear dest (wave-uniform base + lane*16)
__device__ __forceinline__ void gll16(const u16* g, u16* l) {
    __builtin_amdgcn_global_load_lds(
        (const __attribute__((address_space(1))) void*)g,
        (__attribute__((address_space(3))) void*)l, 16, 0, 0);
}
__device__ __forceinline__ bf16x8 ld8(const u16* p) {
    return *(const bf16x8*)p;
}

// ---------------------------------------------------------------------------
// merged preprocessing:
//  blocks [0,768):        split feat -> Xhi/Xlo [2048][384]
//  blocks [768,1776):     transpose+split fc1_w (384x2688) -> W1T [2688][384]
//  blocks [1776,2784):    transpose+split fc2_w (2688x384) -> W2T [384][2688]
//  blocks [2784,3808):    patch histogram -> LabT bf16 [4][1024pad][256]
// ---------------------------------------------------------------------------
__device__ __forceinline__ void transpose_split_body(
    const float* __restrict__ In, int R, int C, int bx, int by,
    u16* __restrict__ OutHi, u16* __restrict__ OutLo, float (*tile)[33])
{
    int cx = bx * 32, ry = by * 32;
    int tr = threadIdx.x >> 5, tc = threadIdx.x & 31;
    #pragma unroll
    for (int i = 0; i < 4; ++i)
        tile[tr + i * 8][tc] = In[(size_t)(ry + tr + i * 8) * C + cx + tc];
    __syncthreads();
    #pragma unroll
    for (int i = 0; i < 4; ++i) {
        int orow = cx + tr + i * 8;
        int ocol = ry + tc;
        float v = tile[tc][tr + i * 8];
        u16 h = f2bf(v);
        OutHi[(size_t)orow * R + ocol] = h;
        OutLo[(size_t)orow * R + ocol] = f2bf(v - bf2f(h));
    }
}

__global__ __launch_bounds__(256) void prep_kernel(
    const float* __restrict__ Xt, const float* __restrict__ Xr,
    const float* __restrict__ fc1w, const float* __restrict__ fc2w,
    const int* __restrict__ labels,
    u16* __restrict__ Xhi, u16* __restrict__ Xlo,
    u16* __restrict__ W1Th, u16* __restrict__ W1Tl,
    u16* __restrict__ W2Th, u16* __restrict__ W2Tl,
    u16* __restrict__ LabT)
{
    __shared__ float tile[32][33];
    __shared__ int hist[NCLS];
    int blk = blockIdx.x, t = threadIdx.x;
    if (blk < 768) {
        int e = (blk * 256 + t) * 4;
        const float* src = (e < 1024 * DIM) ? (Xt + e) : (Xr + e - 1024 * DIM);
        float4 v = *(const float4*)src;
        float x[4] = {v.x, v.y, v.z, v.w};
        u16 h[4], l[4];
        #pragma unroll
        for (int i = 0; i < 4; ++i) {
            h[i] = f2bf(x[i]);
            l[i] = f2bf(x[i] - bf2f(h[i]));
        }
        *(uint2*)(Xhi + e) = make_uint2((u32)h[0] | ((u32)h[1] << 16), (u32)h[2] | ((u32)h[3] << 16));
        *(uint2*)(Xlo + e) = make_uint2((u32)l[0] | ((u32)l[1] << 16), (u32)l[2] | ((u32)l[3] << 16));
    } else if (blk < 1776) {
        int i = blk - 768;
        transpose_split_body(fc1w, DIM, HID, i % (HID / 32), i / (HID / 32), W1Th, W1Tl, tile);
    } else if (blk < 2784) {
        int i = blk - 1776;
        transpose_split_body(fc2w, HID, DIM, i % (DIM / 32), i / (DIM / 32), W2Th, W2Tl, tile);
    } else {
        int bp = blk - 2784;
        int b = bp >> 8, p = bp & 255;
        int py = p >> 4, px = p & 15;
        for (int c = t; c < NCLS; c += 256) hist[c] = 0;
        __syncthreads();
        if (t < PCH * PCH) {
            int dy = t / PCH, dx = t % PCH;
            int y = py * PCH + dy, x = px * PCH + dx;
            int lab = labels[(size_t)b * IMGSZ * IMGSZ + y * IMGSZ + x];
            atomicAdd(&hist[lab], 1);
        }
        __syncthreads();
        const float inv = 1.0f / (PCH * PCH);
        for (int c = t; c < NCLS; c += 256)
            LabT[((size_t)(b << 10) + c) * 256 + p] = f2bf(hist[c] * inv);
    }
}

// ---------------------------------------------------------------------------
// pipelined hi/lo GEMM (NT layout): 128x64 tile, BK=32, 8 waves (4m x 2n),
// 3 LDS buffers, 2-deep prefetch, counted vmcnt, 1 barrier / K-step.
// MODE 0: fc1  X*W1T + b -> GELU -> Hhi/Hlo
// MODE 1: fc2  H*W2T -> f32 partial (split-K via blockIdx.z)
// MODE 2: QK   Zt * Zd^T (gathered) -> S f32
// ---------------------------------------------------------------------------
template<int MODE>
__global__ __launch_bounds__(512) void gemm_pipe(
    const u16* __restrict__ Ahi, const u16* __restrict__ Alo,
    const u16* __restrict__ Bhi, const u16* __restrict__ Blo,
    const float* __restrict__ bias, const int* __restrict__ perms,
    u16* __restrict__ OutHi, u16* __restrict__ OutLo, float* __restrict__ OutF)
{
    constexpr int K  = (MODE == 1) ? HID : DIM;
    constexpr int KS = (MODE == 1) ? HID / 2 : K;
    constexpr int NT = KS / 32;
    constexpr int N  = (MODE == 0) ? HID : (MODE == 1 ? DIM : KTOT);

    __shared__ u16 As_h[3][128 * 32];
    __shared__ u16 As_l[3][128 * 32];
    __shared__ u16 Bs_h[3][64 * 32];
    __shared__ u16 Bs_l[3][64 * 32];

    const int tid  = threadIdx.x;
    const int lane = tid & 63, wid = tid >> 6;
    const int wm = wid >> 1, wn = wid & 1;
    const int n0 = blockIdx.x * 64, m0 = blockIdx.y * 128;

    const u16 *a_h, *a_l, *b_h, *b_l;
    if constexpr (MODE == 0) {
        a_h = Ahi + (size_t)m0 * K;            a_l = Alo + (size_t)m0 * K;
        b_h = Bhi + (size_t)n0 * K;            b_l = Blo + (size_t)n0 * K;
    } else if constexpr (MODE == 1) {
        const int kbase = blockIdx.z * KS;
        a_h = Ahi + (size_t)m0 * K + kbase;    a_l = Alo + (size_t)m0 * K + kbase;
        b_h = Bhi + (size_t)n0 * K + kbase;    b_l = Blo + (size_t)n0 * K + kbase;
    } else {
        const int b = blockIdx.z;
        const int d = n0 >> 8;
        const int apd = (d == 0) ? b : perms[(d - 1) * BSZ + b];
        a_h = Ahi + (size_t)(b * NPATCH + m0) * K;
        a_l = Alo + (size_t)(b * NPATCH + m0) * K;
        b_h = Bhi + (size_t)(1024 + apd * NPATCH + (n0 & 255)) * K;
        b_l = Blo + (size_t)(1024 + apd * NPATCH + (n0 & 255)) * K;
    }

    const int ar = tid >> 2, ac = (tid & 3) * 8;
    const int ub = tid & 255, br = ub >> 2, bc = (ub & 3) * 8;

    auto stage = [&](int buf, int k0) {
        gll16(a_h + (size_t)ar * K + k0 + ac, &As_h[buf][tid * 8]);
        gll16(a_l + (size_t)ar * K + k0 + ac, &As_l[buf][tid * 8]);
        if (tid < 256) gll16(b_h + (size_t)br * K + k0 + bc, &Bs_h[buf][ub * 8]);
        else           gll16(b_l + (size_t)br * K + k0 + bc, &Bs_l[buf][ub * 8]);
    };

    const int l15 = lane & 15, q8 = (lane >> 4) * 8;
    const int arow = wm * 32 + l15;
    const int brow = wn * 32 + l15;

    f32x4 acc[2][2] = {};

    auto compute = [&](int buf) {
        bf16x8 ah[2], al[2], bh[2], bl[2];
        #pragma unroll
        for (int mi = 0; mi < 2; ++mi) {
            ah[mi] = ld8(&As_h[buf][(arow + mi * 16) * 32 + q8]);
            al[mi] = ld8(&As_l[buf][(arow + mi * 16) * 32 + q8]);
        }
        #pragma unroll
        for (int ni = 0; ni < 2; ++ni) {
            bh[ni] = ld8(&Bs_h[buf][(brow + ni * 16) * 32 + q8]);
            bl[ni] = ld8(&Bs_l[buf][(brow + ni * 16) * 32 + q8]);
        }
        #pragma unroll
        for (int mi = 0; mi < 2; ++mi)
            #pragma unroll
            for (int ni = 0; ni < 2; ++ni) {
                acc[mi][ni] = mfma16(ah[mi], bh[ni], acc[mi][ni]);
                acc[mi][ni] = mfma16(ah[mi], bl[ni], acc[mi][ni]);
                acc[mi][ni] = mfma16(al[mi], bh[ni], acc[mi][ni]);
            }
    };

    stage(0, 0);
    stage(1, 32);
    int cur = 0;
    for (int t = 0; t < NT - 1; ++t) {
        asm volatile("s_waitcnt vmcnt(3)" ::: "memory");
        __builtin_amdgcn_s_barrier();
        __builtin_amdgcn_sched_barrier(0);
        if (t + 2 < NT) {
            int nb = cur + 2; if (nb >= 3) nb -= 3;
            stage(nb, (t + 2) * 32);
        }
        compute(cur);
        cur = (cur == 2) ? 0 : cur + 1;
    }
    asm volatile("s_waitcnt vmcnt(0)" ::: "memory");
    __builtin_amdgcn_s_barrier();
    __builtin_amdgcn_sched_barrier(0);
    compute(cur);

    #pragma unroll
    for (int mi = 0; mi < 2; ++mi)
        #pragma unroll
        for (int ni = 0; ni < 2; ++ni)
            #pragma unroll
            for (int r = 0; r < 4; ++r) {
                int gm = m0 + wm * 32 + mi * 16 + ((lane >> 4) << 2) + r;
                int gn = n0 + wn * 32 + ni * 16 + l15;
                float v = acc[mi][ni][r];
                if constexpr (MODE == 0) {
                    v += bias[gn];
                    v = 0.5f * v * (1.0f + erff(v * 0.7071067811865476f));
                    u16 h = f2bf(v);
                    OutHi[(size_t)gm * N + gn] = h;
                    OutLo[(size_t)gm * N + gn] = f2bf(v - bf2f(h));
                } else if constexpr (MODE == 1) {
                    OutF[(size_t)blockIdx.z * (2048 * DIM) + (size_t)gm * N + gn] = v;
                } else {
                    OutF[((size_t)blockIdx.z * NPATCH + gm) * KTOT + gn] = v;
                }
            }
}

// ---------------------------------------------------------------------------
// pipelined PV (bf16 pure): 64x64 tile, BK=32, 8 waves (2m x 4n, 32x16),
// 3 LDS buffers, counted vmcnt(1).  Attn * LabT-gather -> Lhat f32
// ---------------------------------------------------------------------------
__global__ __launch_bounds__(512) void pv_pipe(
    const u16* __restrict__ Attn, const u16* __restrict__ LabT,
    const int* __restrict__ perms, float* __restrict__ Lhat)
{
    constexpr int NT = KTOT / 32;
    __shared__ u16 As[3][64 * 32];
    __shared__ u16 Bs[3][64 * 32];
    __shared__ int ap[8];

    const int tid = threadIdx.x, lane = tid & 63, wid = tid >> 6;
    const int wm = wid >> 2, wn = wid & 3;
    const int n0 = blockIdx.x * 64, m0 = blockIdx.y * 64, b = blockIdx.z;
    if (tid < 8) ap[tid] = (tid == 0) ? b : perms[(tid - 1) * BSZ + b];
    __syncthreads();

    const u16* abase = Attn + (size_t)(b * NPATCH + m0) * KTOT;
    const int cr = (tid & 255) >> 2, cc = ((tid & 255) & 3) * 8;

    auto stage = [&](int buf, int k0) {
        if (tid < 256) {
            gll16(abase + (size_t)cr * KTOT + k0 + cc, &As[buf][(tid & 255) * 8]);
        } else {
            int apd = ap[k0 >> 8];
            gll16(LabT + ((size_t)(apd << 10) + n0 + cr) * 256 + (k0 & 255) + cc,
                  &Bs[buf][(tid & 255) * 8]);
        }
    };

    const int l15 = lane & 15, q8 = (lane >> 4) * 8;
    const int arow = wm * 32 + l15;
    const int brow = wn * 16 + l15;

    f32x4 acc[2] = {};
    auto compute = [&](int buf) {
        bf16x8 bfr = ld8(&Bs[buf][brow * 32 + q8]);
        #pragma unroll
        for (int mi = 0; mi < 2; ++mi) {
            bf16x8 afr = ld8(&As[buf][(arow + mi * 16) * 32 + q8]);
            acc[mi] = mfma16(afr, bfr, acc[mi]);
        }
    };

    stage(0, 0);
    stage(1, 32);
    int cur = 0;
    for (int t = 0; t < NT - 1; ++t) {
        asm volatile("s_waitcnt vmcnt(1)" ::: "memory");
        __builtin_amdgcn_s_barrier();
        __builtin_amdgcn_sched_barrier(0);
        if (t + 2 < NT) {
            int nb = cur + 2; if (nb >= 3) nb -= 3;
            stage(nb, (t + 2) * 32);
        }
        compute(cur);
        cur = (cur == 2) ? 0 : cur + 1;
    }
    asm volatile("s_waitcnt vmcnt(0)" ::: "memory");
    __builtin_amdgcn_s_barrier();
    __builtin_amdgcn_sched_barrier(0);
    compute(cur);

    const int gn = n0 + wn * 16 + l15;
    if (gn < NCLS) {
        #pragma unroll
        for (int mi = 0; mi < 2; ++mi)
            #pragma unroll
            for (int r = 0; r < 4; ++r) {
                int gm = m0 + wm * 32 + mi * 16 + ((lane >> 4) << 2) + r;
                Lhat[((size_t)b * NPATCH + gm) * NCLS + gn] = acc[mi][r];
            }
    }
}

// ---------------------------------------------------------------------------
// split-K reduce + bias + LayerNorm + L2 norm -> Zhi/Zlo; one wave per row
// ---------------------------------------------------------------------------
__device__ __forceinline__ float wave_sum(float v) {
    #pragma unroll
    for (int off = 32; off > 0; off >>= 1) v += __shfl_xor(v, off);
    return v;
}

__global__ __launch_bounds__(256) void ln_l2_kernel(
    const float* __restrict__ P0, const float* __restrict__ fc2b,
    const float* __restrict__ w, const float* __restrict__ b,
    u16* __restrict__ Zhi, u16* __restrict__ Zlo)
{
    const float* P1 = P0 + 2048 * DIM;
    int wid = threadIdx.x >> 6, lane = threadIdx.x & 63;
    int row = blockIdx.x * 4 + wid;
    size_t base = (size_t)row * DIM;
    float x[6];
    float s = 0.0f;
    #pragma unroll
    for (int i = 0; i < 6; ++i) {
        int c = lane + 64 * i;
        x[i] = P0[base + c] + P1[base + c] + fc2b[c];
        s += x[i];
    }
    s = wave_sum(s);
    float mu = s * (1.0f / DIM);
    float vs = 0.0f;
    #pragma unroll
    for (int i = 0; i < 6; ++i) { float d = x[i] - mu; vs += d * d; }
    vs = wave_sum(vs);
    float rstd = 1.0f / sqrtf(vs * (1.0f / DIM) + LN_EPS_F);
    float z[6];
    float n2 = 0.0f;
    #pragma unroll
    for (int i = 0; i < 6; ++i) {
        z[i] = (x[i] - mu) * rstd * w[lane + 64 * i] + b[lane + 64 * i];
        n2 += z[i] * z[i];
    }
    n2 = wave_sum(n2);
    float inv = 1.0f / fmaxf(sqrtf(n2), 1e-12f);
    #pragma unroll
    for (int i = 0; i < 6; ++i) {
        float zn = z[i] * inv;
        u16 h = f2bf(zn);
        Zhi[base + lane + 64 * i] = h;
        Zlo[base + lane + 64 * i] = f2bf(zn - bf2f(h));
    }
}

// ---------------------------------------------------------------------------
// row softmax (2048, 1/beta): S f32 -> Attn bf16
// ---------------------------------------------------------------------------
__global__ __launch_bounds__(256) void softmax_kernel(
    const float* __restrict__ S, u16* __restrict__ A)
{
    int row = blockIdx.x;
    const float* p = S + (size_t)row * KTOT;
    int t = threadIdx.x;
    float v[8];
    float m = -1e30f;
    #pragma unroll
    for (int i = 0; i < 8; ++i) {
        v[i] = p[t + 256 * i] * INV_BETA;
        m = fmaxf(m, v[i]);
    }
    #pragma unroll
    for (int off = 32; off > 0; off >>= 1) m = fmaxf(m, __shfl_xor(m, off));
    __shared__ float redm[4];
    __shared__ float reds[4];
    int wid = t >> 6;
    if ((t & 63) == 0) redm[wid] = m;
    __syncthreads();
    m = fmaxf(fmaxf(redm[0], redm[1]), fmaxf(redm[2], redm[3]));
    float s = 0.0f;
    #pragma unroll
    for (int i = 0; i < 8; ++i) { v[i] = expf(v[i] - m); s += v[i]; }
    s = wave_sum(s);
    if ((t & 63) == 0) reds[wid] = s;
    __syncthreads();
    s = reds[0] + reds[1] + reds[2] + reds[3];
    float inv = 1.0f / s;
    u16* q = A + (size_t)row * KTOT;
    #pragma unroll
    for (int i = 0; i < 8; ++i) q[t + 256 * i] = f2bf(v[i] * inv);
}

// ---------------------------------------------------------------------------
// nearest-upsample 16x16 -> 224x224 with (q,c)->(c,y,x) transpose
// ---------------------------------------------------------------------------
__global__ __launch_bounds__(256) void upsample_kernel(
    const float* __restrict__ Lhat, float* __restrict__ out)
{
    int blk = blockIdx.x;
    int gy = blk & 15;
    int bc = blk >> 4;
    int c = bc % NCLS;
    int b = bc / NCLS;
    __shared__ float vals[GRD];
    int t = threadIdx.x;
    if (t < GRD)
        vals[t] = Lhat[((size_t)(b * NPATCH + gy * GRD + t)) * NCLS + c];
    __syncthreads();
    float* obase = out + ((size_t)(b * NCLS + c) * IMGSZ + gy * PCH) * IMGSZ;
    for (int idx = t; idx < PCH * 56; idx += 256) {
        int x4 = idx % 56, dy = idx / 56;
        int x0 = x4 * 4;
        float4 v = make_float4(vals[x0 / PCH], vals[(x0 + 1) / PCH],
                               vals[(x0 + 2) / PCH], vals[(x0 + 3) / PCH]);
        *(float4*)(obase + dy * IMGSZ + x0) = v;
    }
}

// ---------------------------------------------------------------------------
extern "C" void kernel_launch(void* const* d_in, const int* in_sizes, int n_in,
                              void* d_out, int out_size, void* d_ws, size_t ws_size,
                              hipStream_t stream)
{
    (void)in_sizes; (void)n_in; (void)out_size; (void)ws_size;
    const float* feat_t = (const float*)d_in[0];
    const float* feat_r = (const float*)d_in[1];
    const int*   labels = (const int*)d_in[2];
    const int*   perms  = (const int*)d_in[3];
    const float* fc1_w  = (const float*)d_in[4];
    const float* fc1_b  = (const float*)d_in[5];
    const float* fc2_w  = (const float*)d_in[6];
    const float* fc2_b  = (const float*)d_in[7];
    const float* ln_w   = (const float*)d_in[8];
    const float* ln_b   = (const float*)d_in[9];
    float* out = (float*)d_out;
    char*  W   = (char*)d_ws;

    // workspace layout (bytes)
    u16*   Hhi  = (u16*)(W + 0);            // 11,010,048
    u16*   Hlo  = (u16*)(W + 11010048);     // -> 22,020,096
    float* S    = (float*)(W + 0);          // 8,388,608 (aliases H, post-fc2)
    u16*   Attn = (u16*)(W + 8388608);      // 4,194,304
    float* Lhat = (float*)(W + 12582912);   // 4,096,000
    float* P0   = (float*)(W + 22020096);   // 2 x 3,145,728
    u16*   Zhi  = (u16*)(W + 28311552);     // 1,572,864
    u16*   Zlo  = (u16*)(W + 29884416);     // 1,572,864
    u16*   LabT = (u16*)(W + 31457280);     // 4x1024x256x2 = 2,097,152
    u16*   Xhi  = (u16*)(W + 33554432);     // 1,572,864
    u16*   Xlo  = (u16*)(W + 35127296);     // 1,572,864
    u16*   W1Th = (u16*)(W + 36700160);     // 2,064,384
    u16*   W1Tl = (u16*)(W + 38764544);     // 2,064,384
    u16*   W2Th = (u16*)(W + 40828928);     // 2,064,384
    u16*   W2Tl = (u16*)(W + 42893312);     // 2,064,384

    prep_kernel<<<dim3(3808), dim3(256), 0, stream>>>(
        feat_t, feat_r, fc1_w, fc2_w, labels,
        Xhi, Xlo, W1Th, W1Tl, W2Th, W2Tl, LabT);

    gemm_pipe<0><<<dim3(HID / 64, 2048 / 128), dim3(512), 0, stream>>>(
        Xhi, Xlo, W1Th, W1Tl, fc1_b, nullptr, Hhi, Hlo, nullptr);

    gemm_pipe<1><<<dim3(DIM / 64, 2048 / 128, 2), dim3(512), 0, stream>>>(
        Hhi, Hlo, W2Th, W2Tl, nullptr, nullptr, nullptr, nullptr, P0);

    ln_l2_kernel<<<dim3(2048 / 4), dim3(256), 0, stream>>>(P0, fc2_b, ln_w, ln_b, Zhi, Zlo);

    gemm_pipe<2><<<dim3(KTOT / 64, NPATCH / 128, BSZ), dim3(512), 0, stream>>>(
        Zhi, Zlo, Zhi, Zlo, nullptr, perms, nullptr, nullptr, S);

    softmax_kernel<<<dim3(BSZ * NPATCH), dim3(256), 0, stream>>>(S, Attn);

    pv_pipe<<<dim3(16, NPATCH / 64, BSZ), dim3(512), 0, stream>>>(
        Attn, LabT, perms, Lhat);

    upsample_kernel<<<dim3(BSZ * NCLS * GRD), dim3(256), 0, stream>>>(Lhat, out);
}

// Round 5
// 282.762 us; speedup vs baseline: 2.2256x; 1.0291x over previous
//
#include <hip/hip_runtime.h>

#define BSZ 4
#define NPATCH 256
#define DIM 384
#define HID 2688
#define NCLS 1000
#define KTOT 2048
#define IMGSZ 224
#define PCH 14
#define GRD 16

static constexpr float INV_BETA = 1.0f / 0.07f;
static constexpr float LN_EPS_F = 1e-6f;

typedef unsigned short u16;
typedef unsigned int   u32;
typedef __attribute__((ext_vector_type(8))) __bf16 bf16x8;
typedef __attribute__((ext_vector_type(4))) float  f32x4;

__device__ __forceinline__ u16 f2bf(float f) {
    u32 u = __float_as_uint(f);
    return (u16)((u + 0x7FFFu + ((u >> 16) & 1u)) >> 16);
}
__device__ __forceinline__ float bf2f(u16 h) {
    return __uint_as_float(((u32)h) << 16);
}
__device__ __forceinline__ f32x4 mfma16(bf16x8 a, bf16x8 b, f32x4 c) {
    return __builtin_amdgcn_mfma_f32_16x16x32_bf16(a, b, c, 0, 0, 0);
}
// async global->LDS, 16B/lane, linear dest (wave-uniform base + lane*16)
__device__ __forceinline__ void gll16(const u16* g, u16* l) {
    __builtin_amdgcn_global_load_lds(
        (const __attribute__((address_space(1))) void*)g,
        (__attribute__((address_space(3))) void*)l, 16, 0, 0);
}
__device__ __forceinline__ bf16x8 ld8(const u16* p) {
    return *(const bf16x8*)p;
}
// bank swizzle: granule column (0..3) permuted by row bits 1-2 (involution).
// LDS writes stay LINEAR (global_load_lds requirement); the global SOURCE
// column is pre-swizzled and ds_reads apply the same XOR (rule #21).
__device__ __forceinline__ int swz(int row, int cseg) {
    return cseg ^ ((row >> 1) & 3);
}

// ---------------------------------------------------------------------------
// merged preprocessing (see round 4)
// ---------------------------------------------------------------------------
__device__ __forceinline__ void transpose_split_body(
    const float* __restrict__ In, int R, int C, int bx, int by,
    u16* __restrict__ OutHi, u16* __restrict__ OutLo, float (*tile)[33])
{
    int cx = bx * 32, ry = by * 32;
    int tr = threadIdx.x >> 5, tc = threadIdx.x & 31;
    #pragma unroll
    for (int i = 0; i < 4; ++i)
        tile[tr + i * 8][tc] = In[(size_t)(ry + tr + i * 8) * C + cx + tc];
    __syncthreads();
    #pragma unroll
    for (int i = 0; i < 4; ++i) {
        int orow = cx + tr + i * 8;
        int ocol = ry + tc;
        float v = tile[tc][tr + i * 8];
        u16 h = f2bf(v);
        OutHi[(size_t)orow * R + ocol] = h;
        OutLo[(size_t)orow * R + ocol] = f2bf(v - bf2f(h));
    }
}

__global__ __launch_bounds__(256) void prep_kernel(
    const float* __restrict__ Xt, const float* __restrict__ Xr,
    const float* __restrict__ fc1w, const float* __restrict__ fc2w,
    const int* __restrict__ labels,
    u16* __restrict__ Xhi, u16* __restrict__ Xlo,
    u16* __restrict__ W1Th, u16* __restrict__ W1Tl,
    u16* __restrict__ W2Th, u16* __restrict__ W2Tl,
    u16* __restrict__ LabT)
{
    __shared__ float tile[32][33];
    __shared__ int hist[NCLS];
    int blk = blockIdx.x, t = threadIdx.x;
    if (blk < 768) {
        int e = (blk * 256 + t) * 4;
        const float* src = (e < 1024 * DIM) ? (Xt + e) : (Xr + e - 1024 * DIM);
        float4 v = *(const float4*)src;
        float x[4] = {v.x, v.y, v.z, v.w};
        u16 h[4], l[4];
        #pragma unroll
        for (int i = 0; i < 4; ++i) {
            h[i] = f2bf(x[i]);
            l[i] = f2bf(x[i] - bf2f(h[i]));
        }
        *(uint2*)(Xhi + e) = make_uint2((u32)h[0] | ((u32)h[1] << 16), (u32)h[2] | ((u32)h[3] << 16));
        *(uint2*)(Xlo + e) = make_uint2((u32)l[0] | ((u32)l[1] << 16), (u32)l[2] | ((u32)l[3] << 16));
    } else if (blk < 1776) {
        int i = blk - 768;
        transpose_split_body(fc1w, DIM, HID, i % (HID / 32), i / (HID / 32), W1Th, W1Tl, tile);
    } else if (blk < 2784) {
        int i = blk - 1776;
        transpose_split_body(fc2w, HID, DIM, i % (DIM / 32), i / (DIM / 32), W2Th, W2Tl, tile);
    } else {
        int bp = blk - 2784;
        int b = bp >> 8, p = bp & 255;
        int py = p >> 4, px = p & 15;
        for (int c = t; c < NCLS; c += 256) hist[c] = 0;
        __syncthreads();
        if (t < PCH * PCH) {
            int dy = t / PCH, dx = t % PCH;
            int y = py * PCH + dy, x = px * PCH + dx;
            int lab = labels[(size_t)b * IMGSZ * IMGSZ + y * IMGSZ + x];
            atomicAdd(&hist[lab], 1);
        }
        __syncthreads();
        const float inv = 1.0f / (PCH * PCH);
        for (int c = t; c < NCLS; c += 256)
            LabT[((size_t)(b << 10) + c) * 256 + p] = f2bf(hist[c] * inv);
    }
}

// ---------------------------------------------------------------------------
// pipelined hi/lo GEMM (NT layout): 128x64 tile, BK=32, 8 waves (4m x 2n),
// 3 LDS buffers, 2-deep prefetch, counted vmcnt, bank-swizzled.
// MODE 0: fc1  X*W1T + b -> GELU -> Hhi/Hlo
// MODE 1: fc2  H*W2T -> f32 partial (split-K 4 via blockIdx.z)
// MODE 2: QK   Zt * Zd^T (gathered) -> E = exp((s-1)/beta) bf16
// ---------------------------------------------------------------------------
template<int MODE>
__global__ __launch_bounds__(512) void gemm_pipe(
    const u16* __restrict__ Ahi, const u16* __restrict__ Alo,
    const u16* __restrict__ Bhi, const u16* __restrict__ Blo,
    const float* __restrict__ bias, const int* __restrict__ perms,
    u16* __restrict__ OutHi, u16* __restrict__ OutLo, float* __restrict__ OutF)
{
    constexpr int K  = (MODE == 1) ? HID : DIM;
    constexpr int KS = (MODE == 1) ? HID / 4 : K;
    constexpr int NT = KS / 32;
    constexpr int N  = (MODE == 0) ? HID : (MODE == 1 ? DIM : KTOT);

    __shared__ u16 As_h[3][128 * 32];
    __shared__ u16 As_l[3][128 * 32];
    __shared__ u16 Bs_h[3][64 * 32];
    __shared__ u16 Bs_l[3][64 * 32];

    const int tid  = threadIdx.x;
    const int lane = tid & 63, wid = tid >> 6;
    const int wm = wid >> 1, wn = wid & 1;
    const int n0 = blockIdx.x * 64, m0 = blockIdx.y * 128;

    const u16 *a_h, *a_l, *b_h, *b_l;
    if constexpr (MODE == 0) {
        a_h = Ahi + (size_t)m0 * K;            a_l = Alo + (size_t)m0 * K;
        b_h = Bhi + (size_t)n0 * K;            b_l = Blo + (size_t)n0 * K;
    } else if constexpr (MODE == 1) {
        const int kbase = blockIdx.z * KS;
        a_h = Ahi + (size_t)m0 * K + kbase;    a_l = Alo + (size_t)m0 * K + kbase;
        b_h = Bhi + (size_t)n0 * K + kbase;    b_l = Blo + (size_t)n0 * K + kbase;
    } else {
        const int b = blockIdx.z;
        const int d = n0 >> 8;
        const int apd = (d == 0) ? b : perms[(d - 1) * BSZ + b];
        a_h = Ahi + (size_t)(b * NPATCH + m0) * K;
        a_l = Alo + (size_t)(b * NPATCH + m0) * K;
        b_h = Bhi + (size_t)(1024 + apd * NPATCH + (n0 & 255)) * K;
        b_l = Blo + (size_t)(1024 + apd * NPATCH + (n0 & 255)) * K;
    }

    // staging: LDS dest linear (thread u -> granule (u>>2, u&3)); global source
    // column pre-swizzled so LDS granule (r,c) holds global granule (r, swz(r,c))
    const int ar = tid >> 2, ac = swz(ar, tid & 3) * 8;
    const int ub = tid & 255, br = ub >> 2, bc = swz(br, ub & 3) * 8;

    auto stage = [&](int buf, int k0) {
        gll16(a_h + (size_t)ar * K + k0 + ac, &As_h[buf][tid * 8]);
        gll16(a_l + (size_t)ar * K + k0 + ac, &As_l[buf][tid * 8]);
        if (tid < 256) gll16(b_h + (size_t)br * K + k0 + bc, &Bs_h[buf][ub * 8]);
        else           gll16(b_l + (size_t)br * K + k0 + bc, &Bs_l[buf][ub * 8]);
    };

    const int l15 = lane & 15, cq = lane >> 4;
    // hoisted swizzled read offsets (u16 units, loop-invariant)
    int aoff[2], boff[2];
    #pragma unroll
    for (int mi = 0; mi < 2; ++mi) {
        int row = wm * 32 + l15 + mi * 16;
        aoff[mi] = row * 32 + swz(row, cq) * 8;
    }
    #pragma unroll
    for (int ni = 0; ni < 2; ++ni) {
        int row = wn * 32 + l15 + ni * 16;
        boff[ni] = row * 32 + swz(row, cq) * 8;
    }

    f32x4 acc[2][2] = {};

    auto compute = [&](int buf) {
        bf16x8 ah[2], al[2], bh[2], bl[2];
        #pragma unroll
        for (int mi = 0; mi < 2; ++mi) {
            ah[mi] = ld8(&As_h[buf][aoff[mi]]);
            al[mi] = ld8(&As_l[buf][aoff[mi]]);
        }
        #pragma unroll
        for (int ni = 0; ni < 2; ++ni) {
            bh[ni] = ld8(&Bs_h[buf][boff[ni]]);
            bl[ni] = ld8(&Bs_l[buf][boff[ni]]);
        }
        #pragma unroll
        for (int mi = 0; mi < 2; ++mi)
            #pragma unroll
            for (int ni = 0; ni < 2; ++ni) {
                acc[mi][ni] = mfma16(ah[mi], bh[ni], acc[mi][ni]);
                acc[mi][ni] = mfma16(ah[mi], bl[ni], acc[mi][ni]);
                acc[mi][ni] = mfma16(al[mi], bh[ni], acc[mi][ni]);
            }
    };

    stage(0, 0);
    stage(1, 32);
    int cur = 0;
    for (int t = 0; t < NT - 1; ++t) {
        asm volatile("s_waitcnt vmcnt(3)" ::: "memory");
        __builtin_amdgcn_s_barrier();
        __builtin_amdgcn_sched_barrier(0);
        if (t + 2 < NT) {
            int nb = cur + 2; if (nb >= 3) nb -= 3;
            stage(nb, (t + 2) * 32);
        }
        compute(cur);
        cur = (cur == 2) ? 0 : cur + 1;
    }
    asm volatile("s_waitcnt vmcnt(0)" ::: "memory");
    __builtin_amdgcn_s_barrier();
    __builtin_amdgcn_sched_barrier(0);
    compute(cur);

    #pragma unroll
    for (int mi = 0; mi < 2; ++mi)
        #pragma unroll
        for (int ni = 0; ni < 2; ++ni)
            #pragma unroll
            for (int r = 0; r < 4; ++r) {
                int gm = m0 + wm * 32 + mi * 16 + ((lane >> 4) << 2) + r;
                int gn = n0 + wn * 32 + ni * 16 + l15;
                float v = acc[mi][ni][r];
                if constexpr (MODE == 0) {
                    v += bias[gn];
                    v = 0.5f * v * (1.0f + erff(v * 0.7071067811865476f));
                    u16 h = f2bf(v);
                    OutHi[(size_t)gm * N + gn] = h;
                    OutLo[(size_t)gm * N + gn] = f2bf(v - bf2f(h));
                } else if constexpr (MODE == 1) {
                    OutF[(size_t)blockIdx.z * (2048 * DIM) + (size_t)gm * N + gn] = v;
                } else {
                    // softmax numerator with fixed max: logits = s/beta <= 1/beta
                    float e = expf((v - 1.0f) * INV_BETA);
                    OutHi[((size_t)blockIdx.z * NPATCH + gm) * KTOT + gn] = f2bf(e);
                }
            }
}

// ---------------------------------------------------------------------------
// pipelined PV (bf16): 64x64 tile, BK=32, 8 waves (2m x 4n), bank-swizzled,
// 3 LDS buffers, counted vmcnt(1).  E * LabT-gather / R -> Lhat f32
// ---------------------------------------------------------------------------
__global__ __launch_bounds__(512) void pv_pipe(
    const u16* __restrict__ E, const u16* __restrict__ LabT,
    const int* __restrict__ perms, const float* __restrict__ R,
    float* __restrict__ Lhat)
{
    constexpr int NT = KTOT / 32;
    __shared__ u16 As[3][64 * 32];
    __shared__ u16 Bs[3][64 * 32];
    __shared__ int ap[8];

    const int tid = threadIdx.x, lane = tid & 63, wid = tid >> 6;
    const int wm = wid >> 2, wn = wid & 3;
    const int n0 = blockIdx.x * 64, m0 = blockIdx.y * 64, b = blockIdx.z;
    if (tid < 8) ap[tid] = (tid == 0) ? b : perms[(tid - 1) * BSZ + b];
    __syncthreads();

    const u16* abase = E + (size_t)(b * NPATCH + m0) * KTOT;
    const int cr = (tid & 255) >> 2, ccs = (tid & 255) & 3;
    const int cc = swz(cr, ccs) * 8;

    auto stage = [&](int buf, int k0) {
        if (tid < 256) {
            gll16(abase + (size_t)cr * KTOT + k0 + cc, &As[buf][(tid & 255) * 8]);
        } else {
            int apd = ap[k0 >> 8];
            gll16(LabT + ((size_t)(apd << 10) + n0 + cr) * 256 + (k0 & 255) + cc,
                  &Bs[buf][(tid & 255) * 8]);
        }
    };

    const int l15 = lane & 15, cq = lane >> 4;
    int aoff[2], boff;
    #pragma unroll
    for (int mi = 0; mi < 2; ++mi) {
        int row = wm * 32 + l15 + mi * 16;
        aoff[mi] = row * 32 + swz(row, cq) * 8;
    }
    {
        int row = wn * 16 + l15;
        boff = row * 32 + swz(row, cq) * 8;
    }

    f32x4 acc[2] = {};
    auto compute = [&](int buf) {
        bf16x8 bfr = ld8(&Bs[buf][boff]);
        #pragma unroll
        for (int mi = 0; mi < 2; ++mi) {
            bf16x8 afr = ld8(&As[buf][aoff[mi]]);
            acc[mi] = mfma16(afr, bfr, acc[mi]);
        }
    };

    stage(0, 0);
    stage(1, 32);
    int cur = 0;
    for (int t = 0; t < NT - 1; ++t) {
        asm volatile("s_waitcnt vmcnt(1)" ::: "memory");
        __builtin_amdgcn_s_barrier();
        __builtin_amdgcn_sched_barrier(0);
        if (t + 2 < NT) {
            int nb = cur + 2; if (nb >= 3) nb -= 3;
            stage(nb, (t + 2) * 32);
        }
        compute(cur);
        cur = (cur == 2) ? 0 : cur + 1;
    }
    asm volatile("s_waitcnt vmcnt(0)" ::: "memory");
    __builtin_amdgcn_s_barrier();
    __builtin_amdgcn_sched_barrier(0);
    compute(cur);

    const int gn = n0 + wn * 16 + l15;
    if (gn < NCLS) {
        #pragma unroll
        for (int mi = 0; mi < 2; ++mi)
            #pragma unroll
            for (int r = 0; r < 4; ++r) {
                int gm = m0 + wm * 32 + mi * 16 + ((lane >> 4) << 2) + r;
                float denom = R[(size_t)b * NPATCH + gm];
                Lhat[((size_t)b * NPATCH + gm) * NCLS + gn] = acc[mi][r] / denom;
            }
    }
}

// ---------------------------------------------------------------------------
// row sums of E (bf16, 2048/row) -> R f32[1024]; deterministic tree reduce
// ---------------------------------------------------------------------------
__device__ __forceinline__ float wave_sum(float v) {
    #pragma unroll
    for (int off = 32; off > 0; off >>= 1) v += __shfl_xor(v, off);
    return v;
}

__global__ __launch_bounds__(256) void rowsum_kernel(
    const u16* __restrict__ E, float* __restrict__ R)
{
    int row = blockIdx.x, t = threadIdx.x;
    uint4 u = *(const uint4*)(E + (size_t)row * KTOT + t * 8);
    float s = bf2f(u.x & 0xffff) + bf2f(u.x >> 16)
            + bf2f(u.y & 0xffff) + bf2f(u.y >> 16)
            + bf2f(u.z & 0xffff) + bf2f(u.z >> 16)
            + bf2f(u.w & 0xffff) + bf2f(u.w >> 16);
    s = wave_sum(s);
    __shared__ float red[4];
    if ((t & 63) == 0) red[t >> 6] = s;
    __syncthreads();
    if (t == 0) R[row] = red[0] + red[1] + red[2] + red[3];
}

// ---------------------------------------------------------------------------
// split-K(4) reduce + bias + LayerNorm + L2 norm -> Zhi/Zlo; one wave per row
// ---------------------------------------------------------------------------
__global__ __launch_bounds__(256) void ln_l2_kernel(
    const float* __restrict__ P0, const float* __restrict__ fc2b,
    const float* __restrict__ w, const float* __restrict__ b,
    u16* __restrict__ Zhi, u16* __restrict__ Zlo)
{
    const float* P1 = P0 + 1 * 2048 * DIM;
    const float* P2 = P0 + 2 * 2048 * DIM;
    const float* P3 = P0 + 3 * 2048 * DIM;
    int wid = threadIdx.x >> 6, lane = threadIdx.x & 63;
    int row = blockIdx.x * 4 + wid;
    size_t base = (size_t)row * DIM;
    float x[6];
    float s = 0.0f;
    #pragma unroll
    for (int i = 0; i < 6; ++i) {
        int c = lane + 64 * i;
        x[i] = ((P0[base + c] + P1[base + c]) + (P2[base + c] + P3[base + c])) + fc2b[c];
        s += x[i];
    }
    s = wave_sum(s);
    float mu = s * (1.0f / DIM);
    float vs = 0.0f;
    #pragma unroll
    for (int i = 0; i < 6; ++i) { float d = x[i] - mu; vs += d * d; }
    vs = wave_sum(vs);
    float rstd = 1.0f / sqrtf(vs * (1.0f / DIM) + LN_EPS_F);
    float z[6];
    float n2 = 0.0f;
    #pragma unroll
    for (int i = 0; i < 6; ++i) {
        z[i] = (x[i] - mu) * rstd * w[lane + 64 * i] + b[lane + 64 * i];
        n2 += z[i] * z[i];
    }
    n2 = wave_sum(n2);
    float inv = 1.0f / fmaxf(sqrtf(n2), 1e-12f);
    #pragma unroll
    for (int i = 0; i < 6; ++i) {
        float zn = z[i] * inv;
        u16 h = f2bf(zn);
        Zhi[base + lane + 64 * i] = h;
        Zlo[base + lane + 64 * i] = f2bf(zn - bf2f(h));
    }
}

// ---------------------------------------------------------------------------
// nearest-upsample 16x16 -> 224x224 with (q,c)->(c,y,x) transpose
// ---------------------------------------------------------------------------
__global__ __launch_bounds__(256) void upsample_kernel(
    const float* __restrict__ Lhat, float* __restrict__ out)
{
    int blk = blockIdx.x;
    int gy = blk & 15;
    int bc = blk >> 4;
    int c = bc % NCLS;
    int b = bc / NCLS;
    __shared__ float vals[GRD];
    int t = threadIdx.x;
    if (t < GRD)
        vals[t] = Lhat[((size_t)(b * NPATCH + gy * GRD + t)) * NCLS + c];
    __syncthreads();
    float* obase = out + ((size_t)(b * NCLS + c) * IMGSZ + gy * PCH) * IMGSZ;
    for (int idx = t; idx < PCH * 56; idx += 256) {
        int x4 = idx % 56, dy = idx / 56;
        int x0 = x4 * 4;
        float4 v = make_float4(vals[x0 / PCH], vals[(x0 + 1) / PCH],
                               vals[(x0 + 2) / PCH], vals[(x0 + 3) / PCH]);
        *(float4*)(obase + dy * IMGSZ + x0) = v;
    }
}

// ---------------------------------------------------------------------------
extern "C" void kernel_launch(void* const* d_in, const int* in_sizes, int n_in,
                              void* d_out, int out_size, void* d_ws, size_t ws_size,
                              hipStream_t stream)
{
    (void)in_sizes; (void)n_in; (void)out_size; (void)ws_size;
    const float* feat_t = (const float*)d_in[0];
    const float* feat_r = (const float*)d_in[1];
    const int*   labels = (const int*)d_in[2];
    const int*   perms  = (const int*)d_in[3];
    const float* fc1_w  = (const float*)d_in[4];
    const float* fc1_b  = (const float*)d_in[5];
    const float* fc2_w  = (const float*)d_in[6];
    const float* fc2_b  = (const float*)d_in[7];
    const float* ln_w   = (const float*)d_in[8];
    const float* ln_b   = (const float*)d_in[9];
    float* out = (float*)d_out;
    char*  W   = (char*)d_ws;

    // workspace layout (bytes)
    u16*   Hhi  = (u16*)(W + 0);            // 11,010,048
    u16*   Hlo  = (u16*)(W + 11010048);     // -> 22,020,096
    u16*   E    = (u16*)(W + 0);            // 4,194,304 (aliases H, post-fc2)
    float* R    = (float*)(W + 4194304);    // 4,096 -> 4,198,400
    float* Lhat = (float*)(W + 4718592);    // 4,096,000 -> 8,814,592
    float* P0   = (float*)(W + 22020096);   // 4 x 3,145,728 -> 34,603,008
    u16*   Zhi  = (u16*)(W + 34603008);     // 1,572,864
    u16*   Zlo  = (u16*)(W + 36175872);     // 1,572,864
    u16*   LabT = (u16*)(W + 37748736);     // 2,097,152
    u16*   Xhi  = (u16*)(W + 39845888);     // 1,572,864
    u16*   Xlo  = (u16*)(W + 41418752);     // 1,572,864
    u16*   W1Th = (u16*)(W + 42991616);     // 2,064,384
    u16*   W1Tl = (u16*)(W + 45056000);     // 2,064,384
    u16*   W2Th = (u16*)(W + 47120384);     // 2,064,384
    u16*   W2Tl = (u16*)(W + 49184768);     // 2,064,384

    prep_kernel<<<dim3(3808), dim3(256), 0, stream>>>(
        feat_t, feat_r, fc1_w, fc2_w, labels,
        Xhi, Xlo, W1Th, W1Tl, W2Th, W2Tl, LabT);

    gemm_pipe<0><<<dim3(HID / 64, 2048 / 128), dim3(512), 0, stream>>>(
        Xhi, Xlo, W1Th, W1Tl, fc1_b, nullptr, Hhi, Hlo, nullptr);

    gemm_pipe<1><<<dim3(DIM / 64, 2048 / 128, 4), dim3(512), 0, stream>>>(
        Hhi, Hlo, W2Th, W2Tl, nullptr, nullptr, nullptr, nullptr, P0);

    ln_l2_kernel<<<dim3(2048 / 4), dim3(256), 0, stream>>>(P0, fc2_b, ln_w, ln_b, Zhi, Zlo);

    gemm_pipe<2><<<dim3(KTOT / 64, NPATCH / 128, BSZ), dim3(512), 0, stream>>>(
        Zhi, Zlo, Zhi, Zlo, nullptr, perms, E, nullptr, nullptr);

    rowsum_kernel<<<dim3(BSZ * NPATCH), dim3(256), 0, stream>>>(E, R);

    pv_pipe<<<dim3(16, NPATCH / 64, BSZ), dim3(512), 0, stream>>>(
        E, LabT, perms, R, Lhat);

    upsample_kernel<<<dim3(BSZ * NCLS * GRD), dim3(256), 0, stream>>>(Lhat, out);
}